// Round 6
// baseline (1067.872 us; speedup 1.0000x reference)
//
#include <hip/hip_runtime.h>
#include <hip/hip_bf16.h>
#include <math.h>

// ActorGNN R15: final layer rewritten as edge-centric PUSH (src-bucket blocks,
// Hb3 L1-resident, per-graph LDS accumulate -> partials -> reduce). Dual-key
// binning merged (countA2/scatter2x2 bin by dst AND src in one sweep).
// nt-loads reverted (R14 regression). N=100000, E=3200000, G=64.

#define THREADS 256
#define TCSR 512              // threads for k_bucket_csr
#define BSH 8                 // bucket shift: bucket = id>>8 (<=256 nodes each)
#define MAXNB 512             // LDS histogram capacity (N <= 131072)
#define CH_E 4096             // edges per chunk in binning passes
#define CPT 8                 // chunks per thread in k_scanK3 (NCH <= 2048)
#define PSPLIT 4              // sub-blocks per src bucket in k_push

typedef __attribute__((ext_vector_type(8))) short short8;
typedef __attribute__((ext_vector_type(4))) float f32x4;

// ---- bf16 helpers ----
__device__ inline unsigned short f2bf(float f) {
    unsigned int u = __float_as_uint(f);
    return (unsigned short)((u + 0x7fffu + ((u >> 16) & 1u)) >> 16);  // RNE
}
__device__ inline unsigned int pk2bf(float a, float b) {
    return (unsigned int)f2bf(a) | ((unsigned int)f2bf(b) << 16);
}
__device__ inline float bflo(unsigned int u) { return __uint_as_float(u << 16); }
__device__ inline float bfhi(unsigned int u) { return __uint_as_float(u & 0xffff0000u); }
__device__ inline void unpk8(const uint4 u, float* f) {
    f[0] = bflo(u.x); f[1] = bfhi(u.x); f[2] = bflo(u.y); f[3] = bfhi(u.y);
    f[4] = bflo(u.z); f[5] = bfhi(u.z); f[6] = bflo(u.w); f[7] = bfhi(u.w);
}

// ---- Dual-key binning pass A: per-chunk LDS histograms for dst AND src ----
__global__ void k_countA2(const int* __restrict__ src, const int* __restrict__ dst,
                          unsigned short* __restrict__ lpd, unsigned short* __restrict__ lps,
                          int* __restrict__ cnt_d, int* __restrict__ cnt_s,
                          int E, int NB, int NCH) {
    __shared__ int hd[MAXNB];
    __shared__ int hs[MAXNB];
    int t = threadIdx.x, chunk = blockIdx.x;
    for (int h = t; h < NB; h += THREADS) { hd[h] = 0; hs[h] = 0; }
    __syncthreads();
    int e0 = chunk * CH_E, e1 = min(E, e0 + CH_E);
    for (int e = e0 + t; e < e1; e += THREADS) {
        int hD = dst[e] >> BSH;
        lpd[e] = (unsigned short)atomicAdd(&hd[hD], 1);
        int hS = src[e] >> BSH;
        lps[e] = (unsigned short)atomicAdd(&hs[hS], 1);
    }
    __syncthreads();
    for (int h = t; h < NB; h += THREADS) {
        cnt_d[(size_t)h * NCH + chunk] = hd[h];
        cnt_s[(size_t)h * NCH + chunk] = hs[h];
    }
}

// K1: bucket totals
__global__ void k_sumK1(const int* __restrict__ cnt_mat, int* __restrict__ bucket_tot, int NCH) {
    __shared__ int red[THREADS];
    int b = blockIdx.x, t = threadIdx.x;
    int s = 0;
    for (int c = t; c < NCH; c += THREADS) s += cnt_mat[(size_t)b * NCH + c];
    red[t] = s;
    __syncthreads();
    for (int off = THREADS / 2; off > 0; off >>= 1) {
        if (t < off) red[t] += red[t + off];
        __syncthreads();
    }
    if (t == 0) bucket_tot[b] = red[0];
}

// K2: single block exclusive scan of NB bucket totals -> bucket_base; [NB]=E.
// Also sets rowptr[N]=E (k_bucket_csr only writes rowptr[node] for node<N).
__global__ void k_scanK2(const int* __restrict__ bucket_tot, int* __restrict__ bucket_base,
                         int* __restrict__ rowptr, int NB, int E, int N) {
    __shared__ int sh[MAXNB];
    int t = threadIdx.x;  // 512
    int v = (t < NB) ? bucket_tot[t] : 0;
    sh[t] = v;
    __syncthreads();
    for (int off = 1; off < MAXNB; off <<= 1) {
        int u = (t >= off) ? sh[t - off] : 0;
        __syncthreads();
        sh[t] += u;
        __syncthreads();
    }
    if (t < NB) bucket_base[t] = sh[t] - v;
    if (t == 0) { bucket_base[NB] = E; rowptr[N] = E; }
}

// K3: per-bucket exclusive scan over chunks + bucket base -> offs (IN PLACE
// over cnt: each thread reads its CPT entries into regs before writing).
__global__ void k_scanK3(int* __restrict__ cnt_mat, const int* __restrict__ bucket_base,
                         int NCH) {
    __shared__ int sh[THREADS];
    int b = blockIdx.x, t = threadIdx.x;
    int c0 = t * CPT;
    int v[CPT];
    int s = 0;
#pragma unroll
    for (int k = 0; k < CPT; ++k) {
        int c = c0 + k;
        v[k] = (c < NCH) ? cnt_mat[(size_t)b * NCH + c] : 0;
        s += v[k];
    }
    sh[t] = s;
    __syncthreads();
    for (int off = 1; off < THREADS; off <<= 1) {
        int u = (t >= off) ? sh[t - off] : 0;
        __syncthreads();
        sh[t] += u;
        __syncthreads();
    }
    int run = bucket_base[b] + sh[t] - s;
#pragma unroll
    for (int k = 0; k < CPT; ++k) {
        int c = c0 + k;
        if (c < NCH) { cnt_mat[(size_t)b * NCH + c] = run; run += v[k]; }
    }
}

// Pass B: deterministic dual scatter. pos = offs[bucket][chunk] + lp.
// dst-sorted word: (src<<8)|(dst&255); src-sorted word: (dst<<8)|(src&255).
__global__ void k_scatter2x2(const int* __restrict__ src, const int* __restrict__ dst,
                             const unsigned short* __restrict__ lpd,
                             const unsigned short* __restrict__ lps,
                             const int* __restrict__ offs_d, const int* __restrict__ offs_s,
                             unsigned int* __restrict__ bedges_d,
                             unsigned int* __restrict__ bedges_s,
                             int E, int NB, int NCH) {
    __shared__ int od[MAXNB];
    __shared__ int osrc[MAXNB];
    int t = threadIdx.x, chunk = blockIdx.x;
    for (int h = t; h < NB; h += THREADS) {
        od[h] = offs_d[(size_t)h * NCH + chunk];
        osrc[h] = offs_s[(size_t)h * NCH + chunk];
    }
    __syncthreads();
    int e0 = chunk * CH_E, e1 = min(E, e0 + CH_E);
    for (int e = e0 + t; e < e1; e += THREADS) {
        int s = src[e], d = dst[e];
        int posd = od[d >> BSH] + (int)lpd[e];
        bedges_d[posd] = ((unsigned int)s << BSH) | (unsigned int)(d & ((1 << BSH) - 1));
        int poss = osrc[s >> BSH] + (int)lps[e];
        bedges_s[poss] = ((unsigned int)d << BSH) | (unsigned int)(s & ((1 << BSH) - 1));
    }
}

// Block = dst bucket (<=256 nodes), 512 threads: LDS histogram -> rowptr, dinv,
// bd[n]={dinv, batch}; place srcs into csr_src.
__global__ void k_bucket_csr(const unsigned int* __restrict__ bedges,
                             const int* __restrict__ bucket_base,
                             const int* __restrict__ batch,
                             int* __restrict__ rowptr, float* __restrict__ dinv,
                             float2* __restrict__ bd,
                             int* __restrict__ csr_src, int N) {
    __shared__ int hist[256];
    __shared__ int sc[256];
    __shared__ int cur[256];
    int t = threadIdx.x;   // 0..511
    int b = blockIdx.x;
    int base = bucket_base[b];
    int end = bucket_base[b + 1];
    if (t < 256) hist[t] = 0;
    __syncthreads();
    for (int i = base + t; i < end; i += TCSR)
        atomicAdd(&hist[bedges[i] & 255], 1);
    __syncthreads();
    int c = 0;
    if (t < 256) { c = hist[t]; sc[t] = c; }
    __syncthreads();
    for (int off = 1; off < 256; off <<= 1) {
        int u = (t >= off && t < 256) ? sc[t - off] : 0;
        __syncthreads();
        if (t < 256) sc[t] += u;
        __syncthreads();
    }
    if (t < 256) {
        int excl = sc[t] - c;
        int node = (b << BSH) + t;
        if (node < N) {
            rowptr[node] = base + excl;
            float dv = (float)(1.0 / sqrt((double)(c + 1)));
            dinv[node] = dv;
            bd[node] = make_float2(dv, __int_as_float(batch[node]));
        }
        cur[t] = excl;
    }
    __syncthreads();
    for (int i = base + t; i < end; i += TCSR) {
        unsigned int u = bedges[i];
        int ln = (int)(u & 255);
        int p = atomicAdd(&cur[ln], 1);
        csr_src[base + p] = (int)(u >> BSH);
    }
}

// Row-per-thread GEMM: Hb1[n] = bf16((x[n] @ W1) * dinv[n]); W1^T staged in LDS.
__global__ __launch_bounds__(256) void k_gemm1(const float* __restrict__ X,
                        const float* __restrict__ W,
                        const float* __restrict__ dinv, unsigned short* __restrict__ H, int N) {
    __shared__ float Wt[16 * 128];   // Wt[j][k] = W[k][j]
    int t = threadIdx.x;
    for (int i = t; i < 16 * 128; i += THREADS) {
        int j = i >> 7, k = i & 127;
        Wt[i] = W[k * 16 + j];
    }
    __syncthreads();
    int row = blockIdx.x * THREADS + t;
    if (row >= N) return;
    const float4* xr = (const float4*)(X + (size_t)row * 128);
    float acc[16];
#pragma unroll
    for (int j = 0; j < 16; ++j) acc[j] = 0.0f;
#pragma unroll 4
    for (int k4 = 0; k4 < 32; ++k4) {
        float4 xv = xr[k4];
#pragma unroll
        for (int j = 0; j < 16; ++j) {
            const float4 wv = *(const float4*)&Wt[j * 128 + k4 * 4];  // uniform -> broadcast
            acc[j] += xv.x * wv.x + xv.y * wv.y + xv.z * wv.z + xv.w * wv.w;
        }
    }
    float di = dinv[row];
    uint4 oa, ob;
    oa.x = pk2bf(acc[0] * di, acc[1] * di);
    oa.y = pk2bf(acc[2] * di, acc[3] * di);
    oa.z = pk2bf(acc[4] * di, acc[5] * di);
    oa.w = pk2bf(acc[6] * di, acc[7] * di);
    ob.x = pk2bf(acc[8] * di, acc[9] * di);
    ob.y = pk2bf(acc[10] * di, acc[11] * di);
    ob.z = pk2bf(acc[12] * di, acc[13] * di);
    ob.w = pk2bf(acc[14] * di, acc[15] * di);
    uint4* outr = (uint4*)(H + (size_t)row * 16);
    outr[0] = oa;
    outr[1] = ob;
}

// Pull from bf16 table: 8 features per lane (16B gathers), S-way edge split
// per node (strided), partials combined via shfl_xor. Group = LPN*S lanes.
// t = dinv[n]*(sum_{e->n} Hb[src] + Hb[n])
// MODE 1: bf16 out = relu(t+b)*dinv (L1 out, pre-scaled for next pull)
// MODE 2: fp32 out = t              (L2 pre-GEMM aggregate)
template<int F, int MODE, int S>
__global__ __launch_bounds__(256) void k_pull(
        const int* __restrict__ rowptr, const int* __restrict__ csr_src,
        const float* __restrict__ dinv, const unsigned short* __restrict__ Hb,
        const float* __restrict__ bias, void* __restrict__ outp, int N) {
    const int LPN = F / 8;           // feature lanes per node
    const int GRP = LPN * S;         // lanes per node (8 for both configs)
    const int NPB = THREADS / GRP;   // nodes per block
    int t = threadIdx.x;
    int idx = t % GRP;
    int fl = idx % LPN;              // feature sub-lane (adjacent lanes share edge)
    int s  = idx / LPN;              // edge split index
    int fo = fl * 8;
    int node = blockIdx.x * NPB + t / GRP;

    float acc[8] = {0.f, 0.f, 0.f, 0.f, 0.f, 0.f, 0.f, 0.f};
    if (node < N) {
        int beg = rowptr[node], end = rowptr[node + 1];
        int i = beg + s;
        for (; i + 3 * S < end; i += 4 * S) {
            int s0 = csr_src[i];
            int s1 = csr_src[i + S];
            int s2 = csr_src[i + 2 * S];
            int s3 = csr_src[i + 3 * S];
            uint4 g0 = *(const uint4*)(Hb + (size_t)s0 * F + fo);
            uint4 g1 = *(const uint4*)(Hb + (size_t)s1 * F + fo);
            uint4 g2 = *(const uint4*)(Hb + (size_t)s2 * F + fo);
            uint4 g3 = *(const uint4*)(Hb + (size_t)s3 * F + fo);
            float f0[8], f1[8], f2[8], f3[8];
            unpk8(g0, f0); unpk8(g1, f1); unpk8(g2, f2); unpk8(g3, f3);
#pragma unroll
            for (int j = 0; j < 8; ++j) acc[j] += (f0[j] + f1[j]) + (f2[j] + f3[j]);
        }
        for (; i < end; i += S) {
            int sv = csr_src[i];
            uint4 g = *(const uint4*)(Hb + (size_t)sv * F + fo);
            float f[8];
            unpk8(g, f);
#pragma unroll
            for (int j = 0; j < 8; ++j) acc[j] += f[j];
        }
    }
    // combine S edge-split partials (groups of GRP lanes, GRP | 64)
#pragma unroll
    for (int j = 0; j < 8; ++j) {
        if (S >= 2) acc[j] += __shfl_xor(acc[j], LPN);
        if (S >= 4) acc[j] += __shfl_xor(acc[j], 2 * LPN);
    }

    if (node < N && s == 0) {
        uint4 gs = *(const uint4*)(Hb + (size_t)node * F + fo);
        float sf[8];
        unpk8(gs, sf);
        float di = dinv[node];
        float tv[8];
#pragma unroll
        for (int j = 0; j < 8; ++j) tv[j] = di * (acc[j] + sf[j]);
        if constexpr (MODE == 1) {
            float w[8];
#pragma unroll
            for (int j = 0; j < 8; ++j) w[j] = fmaxf(tv[j] + bias[fo + j], 0.0f) * di;
            uint4 st;
            st.x = pk2bf(w[0], w[1]); st.y = pk2bf(w[2], w[3]);
            st.z = pk2bf(w[4], w[5]); st.w = pk2bf(w[6], w[7]);
            *(uint4*)((unsigned short*)outp + (size_t)node * F + fo) = st;
        } else {  // MODE 2
            float* of = (float*)outp + (size_t)node * F + fo;
            float4 o0, o1;
            o0.x = tv[0]; o0.y = tv[1]; o0.z = tv[2]; o0.w = tv[3];
            o1.x = tv[4]; o1.y = tv[5]; o1.z = tv[6]; o1.w = tv[7];
            ((float4*)of)[0] = o0; ((float4*)of)[1] = o1;
        }
    }
}

// MFMA MLP: wave handles 16 nodes. Swapped operands keep node on lane&15:
//   GEMM-A: D1 = W2^T(A) x P2^T(B), K=16 padded to 32 (zeros pair with zeros).
//   relu(D1 + b2) -> bf16-pair dwords in wave-local LDS (aTd[j/2][node]).
//   GEMM-B: D2 = W3^T(A) x a^T(B from LDS), K=64 (2 k-steps), M=32 (2 tiles).
// C/D layout (verified): col=lane&15, row=(lane>>4)*4+reg.
__global__ __launch_bounds__(256) void k_mlp(const float* __restrict__ P2,
                      const float* __restrict__ W2, const float* __restrict__ b2,
                      const float* __restrict__ W3, const float* __restrict__ dinv,
                      unsigned short* __restrict__ Hb3, int N) {
    __shared__ unsigned int aTd[4][32][17];  // [wave][j/2][node] bf16-pair
    int t = threadIdx.x;
    int w = t >> 6;          // wave 0..3
    int l = t & 63;
    int g = l >> 4;          // lane group 0..3
    int c = l & 15;          // node / row-col index
    int node = blockIdx.x * 64 + w * 16 + c;
    bool nv = node < N;
    int cn = nv ? node : 0;

    // A-frags: W2^T tiles (row j=16*mi+c, k=8g+e; k>=16 -> 0)
    short8 w2f[4];
#pragma unroll
    for (int mi = 0; mi < 4; ++mi) {
        short8 f = {0, 0, 0, 0, 0, 0, 0, 0};
        if (g < 2) {
            int j = 16 * mi + c;
#pragma unroll
            for (int e = 0; e < 8; ++e)
                f[e] = (short)f2bf(W2[(8 * g + e) * 64 + j]);
        }
        w2f[mi] = f;
    }
    // A-frags: W3^T (row m=16*mt+c, k j=32*kt+8g+e)
    short8 w3f[2][2];
#pragma unroll
    for (int mt = 0; mt < 2; ++mt)
#pragma unroll
        for (int kt = 0; kt < 2; ++kt) {
            short8 f;
#pragma unroll
            for (int e = 0; e < 8; ++e)
                f[e] = (short)f2bf(W3[(32 * kt + 8 * g + e) * 32 + 16 * mt + c]);
            w3f[mt][kt] = f;
        }
    // b2 for this lane's C/D rows: j = 16*mi + 4*g + r
    float b2v[16];
#pragma unroll
    for (int mi = 0; mi < 4; ++mi)
#pragma unroll
        for (int r = 0; r < 4; ++r)
            b2v[4 * mi + r] = b2[16 * mi + 4 * g + r];

    // B-frag: P2^T (col=node(c), k=8g+e; k>=16 -> 0)
    short8 pf = {0, 0, 0, 0, 0, 0, 0, 0};
    if (g < 2) {
        const float4* pr = (const float4*)(P2 + (size_t)cn * 16 + 8 * g);
        float4 p0 = pr[0], p1 = pr[1];
        pf[0] = (short)f2bf(p0.x); pf[1] = (short)f2bf(p0.y);
        pf[2] = (short)f2bf(p0.z); pf[3] = (short)f2bf(p0.w);
        pf[4] = (short)f2bf(p1.x); pf[5] = (short)f2bf(p1.y);
        pf[6] = (short)f2bf(p1.z); pf[7] = (short)f2bf(p1.w);
    }

    // GEMM-A: acc1[mi] = W2^T[16mi..] x P2^T  (D1[j][node])
    f32x4 zero = {0.f, 0.f, 0.f, 0.f};
    f32x4 acc1[4];
#pragma unroll
    for (int mi = 0; mi < 4; ++mi)
        acc1[mi] = __builtin_amdgcn_mfma_f32_16x16x32_bf16(w2f[mi], pf, zero, 0, 0, 0);

    // relu + bias -> LDS as bf16-pair dwords: j-pair (16mi+4g, +1) -> row 8mi+2g
#pragma unroll
    for (int mi = 0; mi < 4; ++mi) {
        float a0 = fmaxf(acc1[mi][0] + b2v[4 * mi + 0], 0.f);
        float a1 = fmaxf(acc1[mi][1] + b2v[4 * mi + 1], 0.f);
        float a2 = fmaxf(acc1[mi][2] + b2v[4 * mi + 2], 0.f);
        float a3 = fmaxf(acc1[mi][3] + b2v[4 * mi + 3], 0.f);
        aTd[w][8 * mi + 2 * g][c]     = pk2bf(a0, a1);
        aTd[w][8 * mi + 2 * g + 1][c] = pk2bf(a2, a3);
    }
    __syncthreads();  // waves touch only their own slice; barrier for LDS visibility

    // B-frags: a^T from LDS; elem pair (2i,2i+1) <-> j = 32kt+8g+2i -> row 16kt+4g+i
    short8 bfr[2];
#pragma unroll
    for (int kt = 0; kt < 2; ++kt) {
        short8 f;
#pragma unroll
        for (int i = 0; i < 4; ++i) {
            unsigned int d = aTd[w][16 * kt + 4 * g + i][c];
            f[2 * i]     = (short)(d & 0xffffu);
            f[2 * i + 1] = (short)(d >> 16);
        }
        bfr[kt] = f;
    }

    // GEMM-B: acc2[mt] = sum_kt W3^T x a^T  (D2[m][node])
    f32x4 acc2[2] = {{0.f, 0.f, 0.f, 0.f}, {0.f, 0.f, 0.f, 0.f}};
#pragma unroll
    for (int mt = 0; mt < 2; ++mt)
#pragma unroll
        for (int kt = 0; kt < 2; ++kt)
            acc2[mt] = __builtin_amdgcn_mfma_f32_16x16x32_bf16(w3f[mt][kt], bfr[kt], acc2[mt], 0, 0, 0);

    // store: m = 16mt + 4g + r, Hb3[node][m] bf16 (dword pairs, 8B-aligned)
    if (nv) {
        float di = dinv[node];
        unsigned short* o = Hb3 + (size_t)node * 32;
#pragma unroll
        for (int mt = 0; mt < 2; ++mt) {
            *(unsigned int*)(o + 16 * mt + 4 * g)     = pk2bf(acc2[mt][0] * di, acc2[mt][1] * di);
            *(unsigned int*)(o + 16 * mt + 4 * g + 2) = pk2bf(acc2[mt][2] * di, acc2[mt][3] * di);
        }
    }
}

// Edge-centric PUSH of layer-3 aggregate + pool. Block = (src bucket, part):
// Hb3 rows for the bucket are L1-resident (16KB); per edge gather only 8B
// bd[dst]={dinv,batch} (800KB, L2-hot). Accumulate dinv[dst]*Hb3[src] into
// LDS acc[64][33]; part 0 also adds self terms dinv[n]*Hb3[n]. Flush to
// per-block partials (non-atomic). 4 lanes/edge (8 features each).
__global__ __launch_bounds__(256) void k_push(
        const unsigned int* __restrict__ bsrc, const int* __restrict__ bbase_s,
        const float2* __restrict__ bd, const unsigned short* __restrict__ Hb3,
        float* __restrict__ partials, int N) {
    __shared__ float acc[64][33];
    int t = threadIdx.x;
    int bid = blockIdx.x;
    int b = bid >> 2, p = bid & 3;
    for (int i = t; i < 64 * 33; i += THREADS) ((float*)acc)[i] = 0.0f;
    __syncthreads();
    int e0 = bbase_s[b], e1 = bbase_s[b + 1];
    int len = e1 - e0;
    int s0 = e0 + (int)(((long long)len * p) >> 2);
    int s1 = e0 + (int)(((long long)len * (p + 1)) >> 2);
    int q = t & 3, fo = q * 8;
    for (int i = s0 + (t >> 2); i < s1; i += 64) {
        unsigned int w = bsrc[i];
        int srcn = (b << BSH) | (int)(w & 255u);
        int dstn = (int)(w >> BSH);
        float2 v = bd[dstn];
        float di = v.x;
        int g = __float_as_int(v.y);
        uint4 gr = *(const uint4*)(Hb3 + (size_t)srcn * 32 + fo);
        float f[8];
        unpk8(gr, f);
#pragma unroll
        for (int j = 0; j < 8; ++j) atomicAdd(&acc[g][fo + j], di * f[j]);
    }
    // self terms for this bucket's nodes (rows already hot in L1)
    if (p == 0) {
        int n0 = b << BSH;
        int n1 = min(N, n0 + 256);
        for (int n = n0 + (t >> 2); n < n1; n += 64) {
            float2 v = bd[n];
            float di = v.x;
            int g = __float_as_int(v.y);
            uint4 gr = *(const uint4*)(Hb3 + (size_t)n * 32 + fo);
            float f[8];
            unpk8(gr, f);
#pragma unroll
            for (int j = 0; j < 8; ++j) atomicAdd(&acc[g][fo + j], di * f[j]);
        }
    }
    __syncthreads();
    float* out = partials + (size_t)bid * 2048;
    for (int i = t; i < 2048; i += THREADS) out[i] = acc[i >> 5][i & 31];
}

// Reduce per-block partials -> sums (sums pre-zeroed; 4 range-atomics per slot)
__global__ void k_reduce(const float* __restrict__ partials, float* __restrict__ sums,
                         int NBLK) {
    int blk = blockIdx.x;            // 32
    int t = threadIdx.x;             // 256
    int fid = (blk & 7) * 256 + t;   // 0..2047
    int r = blk >> 3;                // 0..3
    int b0 = (int)(((long long)NBLK * r) >> 2);
    int b1 = (int)(((long long)NBLK * (r + 1)) >> 2);
    float s = 0.0f;
    for (int b = b0; b < b1; ++b) s += partials[(size_t)b * 2048 + fid];
    atomicAdd(&sums[fid], s);
}

__global__ void k_zero_f(float* p, int n) {
    int i = blockIdx.x * blockDim.x + threadIdx.x;
    if (i < n) p[i] = 0.0f;
}

// Head: cnt via binary search; pooled = sums/cnt + b3; a=relu(pooled@Wa+ba);
// out=tanh(a@Wo+bo)
__global__ void k_head(const float* __restrict__ sums, const int* __restrict__ batch, int N,
                       const float* __restrict__ b3,
                       const float* __restrict__ Wa, const float* __restrict__ ba,
                       const float* __restrict__ Wo, const float* __restrict__ bo,
                       float* __restrict__ out) {
    int g = blockIdx.x;
    int j = threadIdx.x;  // 64 threads
    int lo = 0, hi = N;
    while (lo < hi) { int m = (lo + hi) >> 1; if (batch[m] < g) lo = m + 1; else hi = m; }
    int start = lo;
    lo = start; hi = N;
    while (lo < hi) { int m = (lo + hi) >> 1; if (batch[m] < g + 1) lo = m + 1; else hi = m; }
    int cnt = lo - start;
    float inv = 1.0f / (float)(cnt > 0 ? cnt : 1);

    __shared__ float p[32];
    __shared__ float a[64];
    if (j < 32) p[j] = sums[g * 32 + j] * inv + b3[j];
    __syncthreads();
    float acc = ba[j];
#pragma unroll
    for (int k = 0; k < 32; ++k) acc += p[k] * Wa[k * 64 + j];
    a[j] = fmaxf(acc, 0.0f);
    __syncthreads();
    if (j < 32) {
        float acc2 = bo[j];
#pragma unroll
        for (int k = 0; k < 64; ++k) acc2 += a[k] * Wo[k * 32 + j];
        out[g * 32 + j] = tanhf(acc2);
    }
}

static inline int cdiv(long long a, int b) { return (int)((a + b - 1) / b); }
static inline size_t align256(size_t x) { return (x + 255) & ~(size_t)255; }

extern "C" void kernel_launch(void* const* d_in, const int* in_sizes, int n_in,
                              void* d_out, int out_size, void* d_ws, size_t ws_size,
                              hipStream_t stream) {
    const float* x     = (const float*)d_in[0];
    const int*   edge  = (const int*)d_in[1];
    const int*   batch = (const int*)d_in[2];
    const float* W1 = (const float*)d_in[3];  const float* b1 = (const float*)d_in[4];
    const float* W2 = (const float*)d_in[5];  const float* b2 = (const float*)d_in[6];
    const float* W3 = (const float*)d_in[7];  const float* b3 = (const float*)d_in[8];
    const float* Wa = (const float*)d_in[9];  const float* ba = (const float*)d_in[10];
    const float* Wo = (const float*)d_in[11]; const float* bo = (const float*)d_in[12];

    const int E = in_sizes[1] / 2;
    const int N = in_sizes[2];
    const int G = 64;
    const int NB = cdiv(N, 1 << BSH);     // 391
    const int NCH = cdiv(E, CH_E);        // 782

    const int* srcp = edge;
    const int* dstp = edge + E;

    // Workspace
    char* base = (char*)d_ws;
    size_t off = 0;
    float* dinv   = (float*)(base + off); off = align256(off + sizeof(float) * N);
    float2* bd    = (float2*)(base + off); off = align256(off + sizeof(float2) * N);
    unsigned short* lpd = (unsigned short*)(base + off); off = align256(off + sizeof(short) * E);
    unsigned short* lps = (unsigned short*)(base + off); off = align256(off + sizeof(short) * E);
    int* cnt_d    = (int*)(base + off); off = align256(off + sizeof(int) * (size_t)NB * NCH);
    int* cnt_s    = (int*)(base + off); off = align256(off + sizeof(int) * (size_t)NB * NCH);
    int* btot_d   = (int*)(base + off); off = align256(off + sizeof(int) * (NB + 1));
    int* bbase_d  = (int*)(base + off); off = align256(off + sizeof(int) * (NB + 1));
    int* btot_s   = (int*)(base + off); off = align256(off + sizeof(int) * (NB + 1));
    int* bbase_s  = (int*)(base + off); off = align256(off + sizeof(int) * (NB + 1));
    unsigned int* bedges_d = (unsigned int*)(base + off); off = align256(off + sizeof(int) * E);
    unsigned int* bedges_s = (unsigned int*)(base + off); off = align256(off + sizeof(int) * E);
    int* rowptr   = (int*)(base + off); off = align256(off + sizeof(int) * (N + 1));
    int* csr_src  = (int*)(base + off); off = align256(off + sizeof(int) * E);
    unsigned short* Hb1 = (unsigned short*)(base + off); off = align256(off + sizeof(short) * (size_t)N * 16);
    unsigned short* Hb2 = (unsigned short*)(base + off); off = align256(off + sizeof(short) * (size_t)N * 16);
    float* P2     = (float*)(base + off); off = align256(off + sizeof(float) * (size_t)N * 16);
    unsigned short* Hb3 = (unsigned short*)(base + off); off = align256(off + sizeof(short) * (size_t)N * 32);
    float* partials = (float*)(base + off); off = align256(off + sizeof(float) * (size_t)(PSPLIT * NB) * 2048);
    float* sums   = (float*)(base + off); off = align256(off + sizeof(float) * G * 32);

    // ---- Dual-key atomic-free binning -> dst-sorted + src-sorted edge words ----
    k_countA2<<<NCH, THREADS, 0, stream>>>(srcp, dstp, lpd, lps, cnt_d, cnt_s, E, NB, NCH);
    k_sumK1<<<NB, THREADS, 0, stream>>>(cnt_d, btot_d, NCH);
    k_sumK1<<<NB, THREADS, 0, stream>>>(cnt_s, btot_s, NCH);
    k_scanK2<<<1, MAXNB, 0, stream>>>(btot_d, bbase_d, rowptr, NB, E, N);
    k_scanK2<<<1, MAXNB, 0, stream>>>(btot_s, bbase_s, rowptr, NB, E, N);
    k_scanK3<<<NB, THREADS, 0, stream>>>(cnt_d, bbase_d, NCH);   // in-place cnt->offs
    k_scanK3<<<NB, THREADS, 0, stream>>>(cnt_s, bbase_s, NCH);
    k_scatter2x2<<<NCH, THREADS, 0, stream>>>(srcp, dstp, lpd, lps, cnt_d, cnt_s,
                                              bedges_d, bedges_s, E, NB, NCH);

    // ---- CSR (rowptr, csr_src, dinv, bd) from dst-sorted edges ----
    k_bucket_csr<<<NB, TCSR, 0, stream>>>(bedges_d, bbase_d, batch, rowptr, dinv, bd, csr_src, N);

    // ---- Layer 1: Hb1 = bf16((x@W1)*dinv); pull16 -> Hb2 = bf16(relu(.+b1)*dinv) ----
    k_gemm1<<<cdiv(N, THREADS), THREADS, 0, stream>>>(x, W1, dinv, Hb1, N);
    k_pull<16, 1, 4><<<cdiv(N, 32), THREADS, 0, stream>>>(rowptr, csr_src, dinv, Hb1, b1, Hb2, N);

    // ---- Layer 2 aggregate at input width: P2 = pull16(Hb2) ----
    k_pull<16, 2, 4><<<cdiv(N, 32), THREADS, 0, stream>>>(rowptr, csr_src, dinv, Hb2, nullptr, P2, N);

    // ---- Fused node MLP (MFMA): Hb3 = bf16((relu(P2@W2+b2)@W3)*dinv) ----
    k_mlp<<<cdiv(N, 64), THREADS, 0, stream>>>(P2, W2, b2, W3, dinv, Hb3, N);

    // ---- Layer 3 aggregate + pool via edge-centric PUSH over src buckets ----
    k_zero_f<<<cdiv(G * 32, THREADS), THREADS, 0, stream>>>(sums, G * 32);
    k_push<<<PSPLIT * NB, THREADS, 0, stream>>>(bedges_s, bbase_s, bd, Hb3, partials, N);
    k_reduce<<<32, THREADS, 0, stream>>>(partials, sums, PSPLIT * NB);

    // ---- Head (adds deferred b3) ----
    k_head<<<G, 64, 0, stream>>>(sums, batch, N, b3, Wa, ba, Wo, bo, (float*)d_out);
}

// Round 7
// 310.383 us; speedup vs baseline: 3.4405x; 3.4405x over previous
//
#include <hip/hip_runtime.h>
#include <hip/hip_bf16.h>
#include <math.h>

// ActorGNN R16: recovery to R12 (best measured, 310.5us) after push/nt/split
// experiments all regressed. Deltas vs R12: (1) P2 stored bf16 (numerically
// identical: k_mlp converted via same RNE f2bf anyway) halving P2 traffic;
// (2) sums zeroing fused into k_scanK2 (one fewer launch).
// N=100000, E=3200000, G=64.

#define THREADS 256
#define TCSR 512              // threads for k_bucket_csr
#define BSH 8                 // bucket shift: bucket = dst>>8 (<=256 nodes each)
#define MAXNB 512             // LDS histogram capacity (N <= 131072)
#define CH_E 2048             // edges per chunk in binning passes
#define CPT 8                 // chunks per thread in k_scanK3 (NCH <= 2048)

typedef __attribute__((ext_vector_type(8))) short short8;
typedef __attribute__((ext_vector_type(4))) float f32x4;

// ---- bf16 helpers ----
__device__ inline unsigned short f2bf(float f) {
    unsigned int u = __float_as_uint(f);
    return (unsigned short)((u + 0x7fffu + ((u >> 16) & 1u)) >> 16);  // RNE
}
__device__ inline unsigned int pk2bf(float a, float b) {
    return (unsigned int)f2bf(a) | ((unsigned int)f2bf(b) << 16);
}
__device__ inline float bflo(unsigned int u) { return __uint_as_float(u << 16); }
__device__ inline float bfhi(unsigned int u) { return __uint_as_float(u & 0xffff0000u); }
__device__ inline void unpk8(const uint4 u, float* f) {
    f[0] = bflo(u.x); f[1] = bfhi(u.x); f[2] = bflo(u.y); f[3] = bfhi(u.y);
    f[4] = bflo(u.z); f[5] = bfhi(u.z); f[6] = bflo(u.w); f[7] = bfhi(u.w);
}

// ---- Atomic-free binning: pass A counts + records local position ----
__global__ void k_countA(const int* __restrict__ dst, unsigned short* __restrict__ lp16,
                         int* __restrict__ cnt_mat, int E, int NB, int NCH) {
    __shared__ int hist[MAXNB];
    int t = threadIdx.x, chunk = blockIdx.x;
    for (int h = t; h < NB; h += THREADS) hist[h] = 0;
    __syncthreads();
    int e0 = chunk * CH_E, e1 = min(E, e0 + CH_E);
    for (int e = e0 + t; e < e1; e += THREADS) {
        int h = dst[e] >> BSH;
        int lp = atomicAdd(&hist[h], 1);
        lp16[e] = (unsigned short)lp;
    }
    __syncthreads();
    for (int h = t; h < NB; h += THREADS) cnt_mat[(size_t)h * NCH + chunk] = hist[h];
}

// K1: bucket totals
__global__ void k_sumK1(const int* __restrict__ cnt_mat, int* __restrict__ bucket_tot, int NCH) {
    __shared__ int red[THREADS];
    int b = blockIdx.x, t = threadIdx.x;
    int s = 0;
    for (int c = t; c < NCH; c += THREADS) s += cnt_mat[(size_t)b * NCH + c];
    red[t] = s;
    __syncthreads();
    for (int off = THREADS / 2; off > 0; off >>= 1) {
        if (t < off) red[t] += red[t + off];
        __syncthreads();
    }
    if (t == 0) bucket_tot[b] = red[0];
}

// K2: single block exclusive scan of NB bucket totals -> bucket_base; [NB]=E.
// Also sets rowptr[N]=E and zeroes sums (independent side work, saves a launch).
__global__ void k_scanK2(const int* __restrict__ bucket_tot, int* __restrict__ bucket_base,
                         int* __restrict__ rowptr, float* __restrict__ sums,
                         int NB, int E, int N, int GS) {
    __shared__ int sh[MAXNB];
    int t = threadIdx.x;  // 512
    for (int i = t; i < GS; i += MAXNB) sums[i] = 0.0f;
    int v = (t < NB) ? bucket_tot[t] : 0;
    sh[t] = v;
    __syncthreads();
    for (int off = 1; off < MAXNB; off <<= 1) {
        int u = (t >= off) ? sh[t - off] : 0;
        __syncthreads();
        sh[t] += u;
        __syncthreads();
    }
    if (t < NB) bucket_base[t] = sh[t] - v;
    if (t == 0) { bucket_base[NB] = E; rowptr[N] = E; }
}

// K3: per-bucket exclusive scan over chunks + bucket base -> offs_mat
__global__ void k_scanK3(const int* __restrict__ cnt_mat, const int* __restrict__ bucket_base,
                         int* __restrict__ offs_mat, int NCH) {
    __shared__ int sh[THREADS];
    int b = blockIdx.x, t = threadIdx.x;
    int c0 = t * CPT;
    int v[CPT];
    int s = 0;
#pragma unroll
    for (int k = 0; k < CPT; ++k) {
        int c = c0 + k;
        v[k] = (c < NCH) ? cnt_mat[(size_t)b * NCH + c] : 0;
        s += v[k];
    }
    sh[t] = s;
    __syncthreads();
    for (int off = 1; off < THREADS; off <<= 1) {
        int u = (t >= off) ? sh[t - off] : 0;
        __syncthreads();
        sh[t] += u;
        __syncthreads();
    }
    int run = bucket_base[b] + sh[t] - s;
#pragma unroll
    for (int k = 0; k < CPT; ++k) {
        int c = c0 + k;
        if (c < NCH) { offs_mat[(size_t)b * NCH + c] = run; run += v[k]; }
    }
}

// Pass B: deterministic scatter. pos = offs[bucket][chunk] + lp. No atomics.
__global__ void k_scatter2(const int* __restrict__ src, const int* __restrict__ dst,
                           const unsigned short* __restrict__ lp16,
                           const int* __restrict__ offs_mat,
                           unsigned int* __restrict__ bedges, int E, int NB, int NCH) {
    __shared__ int offs[MAXNB];
    int t = threadIdx.x, chunk = blockIdx.x;
    for (int h = t; h < NB; h += THREADS) offs[h] = offs_mat[(size_t)h * NCH + chunk];
    __syncthreads();
    int e0 = chunk * CH_E, e1 = min(E, e0 + CH_E);
    for (int e = e0 + t; e < e1; e += THREADS) {
        int d = dst[e];
        int h = d >> BSH;
        int pos = offs[h] + (int)lp16[e];
        bedges[pos] = ((unsigned int)src[e] << BSH) | (unsigned int)(d & ((1 << BSH) - 1));
    }
}

// Block = bucket (<=256 nodes), 512 threads: LDS histogram -> rowptr, dinv;
// place srcs into csr_src.
__global__ void k_bucket_csr(const unsigned int* __restrict__ bedges,
                             const int* __restrict__ bucket_base,
                             int* __restrict__ rowptr, float* __restrict__ dinv,
                             int* __restrict__ csr_src, int N) {
    __shared__ int hist[256];
    __shared__ int sc[256];
    __shared__ int cur[256];
    int t = threadIdx.x;   // 0..511
    int b = blockIdx.x;
    int base = bucket_base[b];
    int end = bucket_base[b + 1];
    if (t < 256) hist[t] = 0;
    __syncthreads();
    for (int i = base + t; i < end; i += TCSR)
        atomicAdd(&hist[bedges[i] & 255], 1);
    __syncthreads();
    int c = 0;
    if (t < 256) { c = hist[t]; sc[t] = c; }
    __syncthreads();
    for (int off = 1; off < 256; off <<= 1) {
        int u = (t >= off && t < 256) ? sc[t - off] : 0;
        __syncthreads();
        if (t < 256) sc[t] += u;
        __syncthreads();
    }
    if (t < 256) {
        int excl = sc[t] - c;
        int node = (b << BSH) + t;
        if (node < N) {
            rowptr[node] = base + excl;
            dinv[node] = (float)(1.0 / sqrt((double)(c + 1)));
        }
        cur[t] = excl;
    }
    __syncthreads();
    for (int i = base + t; i < end; i += TCSR) {
        unsigned int u = bedges[i];
        int ln = (int)(u & 255);
        int p = atomicAdd(&cur[ln], 1);
        csr_src[base + p] = (int)(u >> BSH);
    }
}

// Row-per-thread GEMM: Hb1[n] = bf16((x[n] @ W1) * dinv[n]); W1^T staged in LDS.
__global__ __launch_bounds__(256) void k_gemm1(const float* __restrict__ X,
                        const float* __restrict__ W,
                        const float* __restrict__ dinv, unsigned short* __restrict__ H, int N) {
    __shared__ float Wt[16 * 128];   // Wt[j][k] = W[k][j]
    int t = threadIdx.x;
    for (int i = t; i < 16 * 128; i += THREADS) {
        int j = i >> 7, k = i & 127;
        Wt[i] = W[k * 16 + j];
    }
    __syncthreads();
    int row = blockIdx.x * THREADS + t;
    if (row >= N) return;
    const float4* xr = (const float4*)(X + (size_t)row * 128);
    float acc[16];
#pragma unroll
    for (int j = 0; j < 16; ++j) acc[j] = 0.0f;
#pragma unroll 4
    for (int k4 = 0; k4 < 32; ++k4) {
        float4 xv = xr[k4];
#pragma unroll
        for (int j = 0; j < 16; ++j) {
            const float4 wv = *(const float4*)&Wt[j * 128 + k4 * 4];  // uniform -> broadcast
            acc[j] += xv.x * wv.x + xv.y * wv.y + xv.z * wv.z + xv.w * wv.w;
        }
    }
    float di = dinv[row];
    uint4 oa, ob;
    oa.x = pk2bf(acc[0] * di, acc[1] * di);
    oa.y = pk2bf(acc[2] * di, acc[3] * di);
    oa.z = pk2bf(acc[4] * di, acc[5] * di);
    oa.w = pk2bf(acc[6] * di, acc[7] * di);
    ob.x = pk2bf(acc[8] * di, acc[9] * di);
    ob.y = pk2bf(acc[10] * di, acc[11] * di);
    ob.z = pk2bf(acc[12] * di, acc[13] * di);
    ob.w = pk2bf(acc[14] * di, acc[15] * di);
    uint4* outr = (uint4*)(H + (size_t)row * 16);
    outr[0] = oa;
    outr[1] = ob;
}

// Pull from bf16 table: 8 features per lane (16B gathers), S-way edge split
// per node (strided), partials combined via shfl_xor. Group = LPN*S lanes.
// t = dinv[n]*(sum_{e->n} Hb[src] + Hb[n])
// MODE 1: bf16 out = relu(t+b)*dinv (L1 out, pre-scaled for next pull)
// MODE 2: bf16 out = t              (L2 pre-GEMM aggregate; mlp consumed bf16
//                                    via the same RNE conversion anyway)
// MODE 3: pooled: atomically accumulate t into gsums[batch[n]*32+f]
//         (bias deferred to head: mean(x+b) = mean(x)+b)
template<int F, int MODE, int S>
__global__ __launch_bounds__(256) void k_pull(
        const int* __restrict__ rowptr, const int* __restrict__ csr_src,
        const float* __restrict__ dinv, const unsigned short* __restrict__ Hb,
        const float* __restrict__ bias, void* __restrict__ outp,
        const int* __restrict__ batch, float* __restrict__ gsums,
        int N, int G) {
    const int LPN = F / 8;           // feature lanes per node
    const int GRP = LPN * S;         // lanes per node (8 for both configs)
    const int NPB = THREADS / GRP;   // nodes per block
    int t = threadIdx.x;
    int idx = t % GRP;
    int fl = idx % LPN;              // feature sub-lane (adjacent lanes share edge)
    int s  = idx / LPN;              // edge split index
    int fo = fl * 8;
    int node = blockIdx.x * NPB + t / GRP;

    float acc[8] = {0.f, 0.f, 0.f, 0.f, 0.f, 0.f, 0.f, 0.f};
    if (node < N) {
        int beg = rowptr[node], end = rowptr[node + 1];
        int i = beg + s;
        for (; i + 3 * S < end; i += 4 * S) {
            int s0 = csr_src[i];
            int s1 = csr_src[i + S];
            int s2 = csr_src[i + 2 * S];
            int s3 = csr_src[i + 3 * S];
            uint4 g0 = *(const uint4*)(Hb + (size_t)s0 * F + fo);
            uint4 g1 = *(const uint4*)(Hb + (size_t)s1 * F + fo);
            uint4 g2 = *(const uint4*)(Hb + (size_t)s2 * F + fo);
            uint4 g3 = *(const uint4*)(Hb + (size_t)s3 * F + fo);
            float f0[8], f1[8], f2[8], f3[8];
            unpk8(g0, f0); unpk8(g1, f1); unpk8(g2, f2); unpk8(g3, f3);
#pragma unroll
            for (int j = 0; j < 8; ++j) acc[j] += (f0[j] + f1[j]) + (f2[j] + f3[j]);
        }
        for (; i < end; i += S) {
            int sv = csr_src[i];
            uint4 g = *(const uint4*)(Hb + (size_t)sv * F + fo);
            float f[8];
            unpk8(g, f);
#pragma unroll
            for (int j = 0; j < 8; ++j) acc[j] += f[j];
        }
    }
    // combine S edge-split partials (groups of GRP lanes, GRP | 64)
#pragma unroll
    for (int j = 0; j < 8; ++j) {
        if (S >= 2) acc[j] += __shfl_xor(acc[j], LPN);
        if (S >= 4) acc[j] += __shfl_xor(acc[j], 2 * LPN);
    }

    if constexpr (MODE == 3) {
        // fused global_mean_pool accumulate (batch is sorted: block spans few graphs)
        __shared__ float lsum[4][32];
        __shared__ int g0s;
        for (int z = t; z < 4 * 32; z += THREADS) ((float*)lsum)[z] = 0.0f;
        if (t == 0) g0s = batch[blockIdx.x * NPB];
        __syncthreads();
        int g0 = g0s;
        if (node < N && s == 0) {
            uint4 gs = *(const uint4*)(Hb + (size_t)node * F + fo);
            float sf[8];
            unpk8(gs, sf);
            float di = dinv[node];
            int g = batch[node];
            int r = g - g0;
            if ((unsigned)r < 4u) {
#pragma unroll
                for (int j = 0; j < 8; ++j)
                    atomicAdd(&lsum[r][fo + j], di * (acc[j] + sf[j]));
            } else {  // safety fallback (tiny graphs / unsorted batch)
#pragma unroll
                for (int j = 0; j < 8; ++j)
                    atomicAdd(&gsums[(size_t)g * 32 + fo + j], di * (acc[j] + sf[j]));
            }
        }
        __syncthreads();
        if (t < 128) {
            int r = t >> 5, f = t & 31;
            int g = g0 + r;
            float v = lsum[r][f];
            if (g < G && v != 0.0f) atomicAdd(&gsums[(size_t)g * 32 + f], v);
        }
    } else {
        if (node < N && s == 0) {
            uint4 gs = *(const uint4*)(Hb + (size_t)node * F + fo);
            float sf[8];
            unpk8(gs, sf);
            float di = dinv[node];
            float tv[8];
#pragma unroll
            for (int j = 0; j < 8; ++j) tv[j] = di * (acc[j] + sf[j]);
            if constexpr (MODE == 1) {
                float w[8];
#pragma unroll
                for (int j = 0; j < 8; ++j) w[j] = fmaxf(tv[j] + bias[fo + j], 0.0f) * di;
                uint4 st;
                st.x = pk2bf(w[0], w[1]); st.y = pk2bf(w[2], w[3]);
                st.z = pk2bf(w[4], w[5]); st.w = pk2bf(w[6], w[7]);
                *(uint4*)((unsigned short*)outp + (size_t)node * F + fo) = st;
            } else {  // MODE 2: bf16 aggregate (same RNE quantization mlp applied)
                uint4 st;
                st.x = pk2bf(tv[0], tv[1]); st.y = pk2bf(tv[2], tv[3]);
                st.z = pk2bf(tv[4], tv[5]); st.w = pk2bf(tv[6], tv[7]);
                *(uint4*)((unsigned short*)outp + (size_t)node * F + fo) = st;
            }
        }
    }
}

// MFMA MLP: wave handles 16 nodes. Swapped operands keep node on lane&15:
//   GEMM-A: D1 = W2^T(A) x P2^T(B), K=16 padded to 32 (zeros pair with zeros).
//   relu(D1 + b2) -> bf16-pair dwords in wave-local LDS (aTd[j/2][node]).
//   GEMM-B: D2 = W3^T(A) x a^T(B from LDS), K=64 (2 k-steps), M=32 (2 tiles).
// C/D layout (verified): col=lane&15, row=(lane>>4)*4+reg.
// P2b is bf16: B-frag loads are direct 16B reinterprets (no conversion).
__global__ __launch_bounds__(256) void k_mlp(const unsigned short* __restrict__ P2b,
                      const float* __restrict__ W2, const float* __restrict__ b2,
                      const float* __restrict__ W3, const float* __restrict__ dinv,
                      unsigned short* __restrict__ Hb3, int N) {
    __shared__ unsigned int aTd[4][32][17];  // [wave][j/2][node] bf16-pair
    int t = threadIdx.x;
    int w = t >> 6;          // wave 0..3
    int l = t & 63;
    int g = l >> 4;          // lane group 0..3
    int c = l & 15;          // node / row-col index
    int node = blockIdx.x * 64 + w * 16 + c;
    bool nv = node < N;
    int cn = nv ? node : 0;

    // A-frags: W2^T tiles (row j=16*mi+c, k=8g+e; k>=16 -> 0)
    short8 w2f[4];
#pragma unroll
    for (int mi = 0; mi < 4; ++mi) {
        short8 f = {0, 0, 0, 0, 0, 0, 0, 0};
        if (g < 2) {
            int j = 16 * mi + c;
#pragma unroll
            for (int e = 0; e < 8; ++e)
                f[e] = (short)f2bf(W2[(8 * g + e) * 64 + j]);
        }
        w2f[mi] = f;
    }
    // A-frags: W3^T (row m=16*mt+c, k j=32*kt+8g+e)
    short8 w3f[2][2];
#pragma unroll
    for (int mt = 0; mt < 2; ++mt)
#pragma unroll
        for (int kt = 0; kt < 2; ++kt) {
            short8 f;
#pragma unroll
            for (int e = 0; e < 8; ++e)
                f[e] = (short)f2bf(W3[(32 * kt + 8 * g + e) * 32 + 16 * mt + c]);
            w3f[mt][kt] = f;
        }
    // b2 for this lane's C/D rows: j = 16*mi + 4*g + r
    float b2v[16];
#pragma unroll
    for (int mi = 0; mi < 4; ++mi)
#pragma unroll
        for (int r = 0; r < 4; ++r)
            b2v[4 * mi + r] = b2[16 * mi + 4 * g + r];

    // B-frag: P2b^T (col=node(c), k=8g+e; k>=16 -> 0); direct bf16 reinterpret
    short8 pf = {0, 0, 0, 0, 0, 0, 0, 0};
    if (g < 2) {
        pf = *(const short8*)(P2b + (size_t)cn * 16 + 8 * g);
    }

    // GEMM-A: acc1[mi] = W2^T[16mi..] x P2^T  (D1[j][node])
    f32x4 zero = {0.f, 0.f, 0.f, 0.f};
    f32x4 acc1[4];
#pragma unroll
    for (int mi = 0; mi < 4; ++mi)
        acc1[mi] = __builtin_amdgcn_mfma_f32_16x16x32_bf16(w2f[mi], pf, zero, 0, 0, 0);

    // relu + bias -> LDS as bf16-pair dwords: j-pair (16mi+4g, +1) -> row 8mi+2g
#pragma unroll
    for (int mi = 0; mi < 4; ++mi) {
        float a0 = fmaxf(acc1[mi][0] + b2v[4 * mi + 0], 0.f);
        float a1 = fmaxf(acc1[mi][1] + b2v[4 * mi + 1], 0.f);
        float a2 = fmaxf(acc1[mi][2] + b2v[4 * mi + 2], 0.f);
        float a3 = fmaxf(acc1[mi][3] + b2v[4 * mi + 3], 0.f);
        aTd[w][8 * mi + 2 * g][c]     = pk2bf(a0, a1);
        aTd[w][8 * mi + 2 * g + 1][c] = pk2bf(a2, a3);
    }
    __syncthreads();  // waves touch only their own slice; barrier for LDS visibility

    // B-frags: a^T from LDS; elem pair (2i,2i+1) <-> j = 32kt+8g+2i -> row 16kt+4g+i
    short8 bfr[2];
#pragma unroll
    for (int kt = 0; kt < 2; ++kt) {
        short8 f;
#pragma unroll
        for (int i = 0; i < 4; ++i) {
            unsigned int d = aTd[w][16 * kt + 4 * g + i][c];
            f[2 * i]     = (short)(d & 0xffffu);
            f[2 * i + 1] = (short)(d >> 16);
        }
        bfr[kt] = f;
    }

    // GEMM-B: acc2[mt] = sum_kt W3^T x a^T  (D2[m][node])
    f32x4 acc2[2] = {{0.f, 0.f, 0.f, 0.f}, {0.f, 0.f, 0.f, 0.f}};
#pragma unroll
    for (int mt = 0; mt < 2; ++mt)
#pragma unroll
        for (int kt = 0; kt < 2; ++kt)
            acc2[mt] = __builtin_amdgcn_mfma_f32_16x16x32_bf16(w3f[mt][kt], bfr[kt], acc2[mt], 0, 0, 0);

    // store: m = 16mt + 4g + r, Hb3[node][m] bf16 (dword pairs, 8B-aligned)
    if (nv) {
        float di = dinv[node];
        unsigned short* o = Hb3 + (size_t)node * 32;
#pragma unroll
        for (int mt = 0; mt < 2; ++mt) {
            *(unsigned int*)(o + 16 * mt + 4 * g)     = pk2bf(acc2[mt][0] * di, acc2[mt][1] * di);
            *(unsigned int*)(o + 16 * mt + 4 * g + 2) = pk2bf(acc2[mt][2] * di, acc2[mt][3] * di);
        }
    }
}

// Head: cnt via binary search; pooled = sums/cnt + b3; a=relu(pooled@Wa+ba);
// out=tanh(a@Wo+bo)
__global__ void k_head(const float* __restrict__ sums, const int* __restrict__ batch, int N,
                       const float* __restrict__ b3,
                       const float* __restrict__ Wa, const float* __restrict__ ba,
                       const float* __restrict__ Wo, const float* __restrict__ bo,
                       float* __restrict__ out) {
    int g = blockIdx.x;
    int j = threadIdx.x;  // 64 threads
    int lo = 0, hi = N;
    while (lo < hi) { int m = (lo + hi) >> 1; if (batch[m] < g) lo = m + 1; else hi = m; }
    int start = lo;
    lo = start; hi = N;
    while (lo < hi) { int m = (lo + hi) >> 1; if (batch[m] < g + 1) lo = m + 1; else hi = m; }
    int cnt = lo - start;
    float inv = 1.0f / (float)(cnt > 0 ? cnt : 1);

    __shared__ float p[32];
    __shared__ float a[64];
    if (j < 32) p[j] = sums[g * 32 + j] * inv + b3[j];
    __syncthreads();
    float acc = ba[j];
#pragma unroll
    for (int k = 0; k < 32; ++k) acc += p[k] * Wa[k * 64 + j];
    a[j] = fmaxf(acc, 0.0f);
    __syncthreads();
    if (j < 32) {
        float acc2 = bo[j];
#pragma unroll
        for (int k = 0; k < 64; ++k) acc2 += a[k] * Wo[k * 32 + j];
        out[g * 32 + j] = tanhf(acc2);
    }
}

static inline int cdiv(long long a, int b) { return (int)((a + b - 1) / b); }
static inline size_t align256(size_t x) { return (x + 255) & ~(size_t)255; }

extern "C" void kernel_launch(void* const* d_in, const int* in_sizes, int n_in,
                              void* d_out, int out_size, void* d_ws, size_t ws_size,
                              hipStream_t stream) {
    const float* x     = (const float*)d_in[0];
    const int*   edge  = (const int*)d_in[1];
    const int*   batch = (const int*)d_in[2];
    const float* W1 = (const float*)d_in[3];  const float* b1 = (const float*)d_in[4];
    const float* W2 = (const float*)d_in[5];  const float* b2 = (const float*)d_in[6];
    const float* W3 = (const float*)d_in[7];  const float* b3 = (const float*)d_in[8];
    const float* Wa = (const float*)d_in[9];  const float* ba = (const float*)d_in[10];
    const float* Wo = (const float*)d_in[11]; const float* bo = (const float*)d_in[12];

    const int E = in_sizes[1] / 2;
    const int N = in_sizes[2];
    const int G = 64;
    const int NB = cdiv(N, 1 << BSH);     // 391
    const int NCH = cdiv(E, CH_E);        // 1563

    const int* srcp = edge;
    const int* dstp = edge + E;

    // Workspace
    char* base = (char*)d_ws;
    size_t off = 0;
    float* dinv   = (float*)(base + off); off = align256(off + sizeof(float) * N);
    unsigned short* lp16 = (unsigned short*)(base + off); off = align256(off + sizeof(short) * E);
    int* cnt_mat  = (int*)(base + off); off = align256(off + sizeof(int) * (size_t)NB * NCH);
    int* offs_mat = (int*)(base + off); off = align256(off + sizeof(int) * (size_t)NB * NCH);
    int* btot     = (int*)(base + off); off = align256(off + sizeof(int) * (NB + 1));
    int* bbase    = (int*)(base + off); off = align256(off + sizeof(int) * (NB + 1));
    unsigned int* bedges = (unsigned int*)(base + off); off = align256(off + sizeof(int) * E);
    int* rowptr   = (int*)(base + off); off = align256(off + sizeof(int) * (N + 1));
    int* csr_src  = (int*)(base + off); off = align256(off + sizeof(int) * E);
    unsigned short* Hb1 = (unsigned short*)(base + off); off = align256(off + sizeof(short) * (size_t)N * 16);
    unsigned short* Hb2 = (unsigned short*)(base + off); off = align256(off + sizeof(short) * (size_t)N * 16);
    unsigned short* P2b = (unsigned short*)(base + off); off = align256(off + sizeof(short) * (size_t)N * 16);
    unsigned short* Hb3 = (unsigned short*)(base + off); off = align256(off + sizeof(short) * (size_t)N * 32);
    float* sums   = (float*)(base + off); off = align256(off + sizeof(float) * G * 32);

    // ---- Atomic-free binning -> bucket-sorted bedges ----
    k_countA<<<NCH, THREADS, 0, stream>>>(dstp, lp16, cnt_mat, E, NB, NCH);
    k_sumK1<<<NB, THREADS, 0, stream>>>(cnt_mat, btot, NCH);
    k_scanK2<<<1, MAXNB, 0, stream>>>(btot, bbase, rowptr, sums, NB, E, N, G * 32);
    k_scanK3<<<NB, THREADS, 0, stream>>>(cnt_mat, bbase, offs_mat, NCH);
    k_scatter2<<<NCH, THREADS, 0, stream>>>(srcp, dstp, lp16, offs_mat, bedges, E, NB, NCH);

    // ---- CSR (rowptr, csr_src, dinv) from bucket-sorted edges ----
    k_bucket_csr<<<NB, TCSR, 0, stream>>>(bedges, bbase, rowptr, dinv, csr_src, N);

    // ---- Layer 1: Hb1 = bf16((x@W1)*dinv); pull16 -> Hb2 = bf16(relu(.+b1)*dinv) ----
    k_gemm1<<<cdiv(N, THREADS), THREADS, 0, stream>>>(x, W1, dinv, Hb1, N);
    k_pull<16, 1, 4><<<cdiv(N, 32), THREADS, 0, stream>>>(rowptr, csr_src, dinv, Hb1, b1, Hb2,
                                                          nullptr, nullptr, N, G);

    // ---- Layer 2 aggregate at input width: P2b = bf16(pull16(Hb2)) ----
    k_pull<16, 2, 4><<<cdiv(N, 32), THREADS, 0, stream>>>(rowptr, csr_src, dinv, Hb2, nullptr, P2b,
                                                          nullptr, nullptr, N, G);

    // ---- Fused node MLP (MFMA): Hb3 = bf16((relu(P2b@W2+b2)@W3)*dinv) ----
    k_mlp<<<cdiv(N, 64), THREADS, 0, stream>>>(P2b, W2, b2, W3, dinv, Hb3, N);

    // ---- Layer 3 aggregate fused with pooling: sums[g] += dinv*(agg+self) ----
    k_pull<32, 3, 2><<<cdiv(N, 32), THREADS, 0, stream>>>(rowptr, csr_src, dinv, Hb3, nullptr,
                                                          nullptr, batch, sums, N, G);

    // ---- Head (adds deferred b3) ----
    k_head<<<G, 64, 0, stream>>>(sums, batch, N, b3, Wa, ba, Wo, bo, (float*)d_out);
}

// Round 8
// 307.465 us; speedup vs baseline: 3.4732x; 1.0095x over previous
//
#include <hip/hip_runtime.h>
#include <hip/hip_bf16.h>
#include <math.h>

// ActorGNN R17: R16 + prepass latency fixes: (1) k_bucket_csr 512->1024 thr
// (was 1.5 blk/CU, serial-chain-bound); (2) k_gemm1 4 sub-lanes/row (391->1563
// blocks, was 19% occupancy on a 51MB stream); (3) CH_E 2048->4096 (longer
// scatter write runs, half the cnt/offs traffic). N=100000, E=3200000, G=64.

#define THREADS 256
#define TCSR 1024             // threads for k_bucket_csr
#define BSH 8                 // bucket shift: bucket = dst>>8 (<=256 nodes each)
#define MAXNB 512             // LDS histogram capacity (N <= 131072)
#define CH_E 4096             // edges per chunk in binning passes
#define CPT 8                 // chunks per thread in k_scanK3 (NCH <= 2048)

typedef __attribute__((ext_vector_type(8))) short short8;
typedef __attribute__((ext_vector_type(4))) float f32x4;

// ---- bf16 helpers ----
__device__ inline unsigned short f2bf(float f) {
    unsigned int u = __float_as_uint(f);
    return (unsigned short)((u + 0x7fffu + ((u >> 16) & 1u)) >> 16);  // RNE
}
__device__ inline unsigned int pk2bf(float a, float b) {
    return (unsigned int)f2bf(a) | ((unsigned int)f2bf(b) << 16);
}
__device__ inline float bflo(unsigned int u) { return __uint_as_float(u << 16); }
__device__ inline float bfhi(unsigned int u) { return __uint_as_float(u & 0xffff0000u); }
__device__ inline void unpk8(const uint4 u, float* f) {
    f[0] = bflo(u.x); f[1] = bfhi(u.x); f[2] = bflo(u.y); f[3] = bfhi(u.y);
    f[4] = bflo(u.z); f[5] = bfhi(u.z); f[6] = bflo(u.w); f[7] = bfhi(u.w);
}

// ---- Atomic-free binning: pass A counts + records local position ----
__global__ void k_countA(const int* __restrict__ dst, unsigned short* __restrict__ lp16,
                         int* __restrict__ cnt_mat, int E, int NB, int NCH) {
    __shared__ int hist[MAXNB];
    int t = threadIdx.x, chunk = blockIdx.x;
    for (int h = t; h < NB; h += THREADS) hist[h] = 0;
    __syncthreads();
    int e0 = chunk * CH_E, e1 = min(E, e0 + CH_E);
    for (int e = e0 + t; e < e1; e += THREADS) {
        int h = dst[e] >> BSH;
        int lp = atomicAdd(&hist[h], 1);
        lp16[e] = (unsigned short)lp;
    }
    __syncthreads();
    for (int h = t; h < NB; h += THREADS) cnt_mat[(size_t)h * NCH + chunk] = hist[h];
}

// K1: bucket totals
__global__ void k_sumK1(const int* __restrict__ cnt_mat, int* __restrict__ bucket_tot, int NCH) {
    __shared__ int red[THREADS];
    int b = blockIdx.x, t = threadIdx.x;
    int s = 0;
    for (int c = t; c < NCH; c += THREADS) s += cnt_mat[(size_t)b * NCH + c];
    red[t] = s;
    __syncthreads();
    for (int off = THREADS / 2; off > 0; off >>= 1) {
        if (t < off) red[t] += red[t + off];
        __syncthreads();
    }
    if (t == 0) bucket_tot[b] = red[0];
}

// K2: single block exclusive scan of NB bucket totals -> bucket_base; [NB]=E.
// Also sets rowptr[N]=E and zeroes sums (independent side work, saves a launch).
__global__ void k_scanK2(const int* __restrict__ bucket_tot, int* __restrict__ bucket_base,
                         int* __restrict__ rowptr, float* __restrict__ sums,
                         int NB, int E, int N, int GS) {
    __shared__ int sh[MAXNB];
    int t = threadIdx.x;  // 512
    for (int i = t; i < GS; i += MAXNB) sums[i] = 0.0f;
    int v = (t < NB) ? bucket_tot[t] : 0;
    sh[t] = v;
    __syncthreads();
    for (int off = 1; off < MAXNB; off <<= 1) {
        int u = (t >= off) ? sh[t - off] : 0;
        __syncthreads();
        sh[t] += u;
        __syncthreads();
    }
    if (t < NB) bucket_base[t] = sh[t] - v;
    if (t == 0) { bucket_base[NB] = E; rowptr[N] = E; }
}

// K3: per-bucket exclusive scan over chunks + bucket base -> offs_mat
__global__ void k_scanK3(const int* __restrict__ cnt_mat, const int* __restrict__ bucket_base,
                         int* __restrict__ offs_mat, int NCH) {
    __shared__ int sh[THREADS];
    int b = blockIdx.x, t = threadIdx.x;
    int c0 = t * CPT;
    int v[CPT];
    int s = 0;
#pragma unroll
    for (int k = 0; k < CPT; ++k) {
        int c = c0 + k;
        v[k] = (c < NCH) ? cnt_mat[(size_t)b * NCH + c] : 0;
        s += v[k];
    }
    sh[t] = s;
    __syncthreads();
    for (int off = 1; off < THREADS; off <<= 1) {
        int u = (t >= off) ? sh[t - off] : 0;
        __syncthreads();
        sh[t] += u;
        __syncthreads();
    }
    int run = bucket_base[b] + sh[t] - s;
#pragma unroll
    for (int k = 0; k < CPT; ++k) {
        int c = c0 + k;
        if (c < NCH) { offs_mat[(size_t)b * NCH + c] = run; run += v[k]; }
    }
}

// Pass B: deterministic scatter. pos = offs[bucket][chunk] + lp. No atomics.
__global__ void k_scatter2(const int* __restrict__ src, const int* __restrict__ dst,
                           const unsigned short* __restrict__ lp16,
                           const int* __restrict__ offs_mat,
                           unsigned int* __restrict__ bedges, int E, int NB, int NCH) {
    __shared__ int offs[MAXNB];
    int t = threadIdx.x, chunk = blockIdx.x;
    for (int h = t; h < NB; h += THREADS) offs[h] = offs_mat[(size_t)h * NCH + chunk];
    __syncthreads();
    int e0 = chunk * CH_E, e1 = min(E, e0 + CH_E);
    for (int e = e0 + t; e < e1; e += THREADS) {
        int d = dst[e];
        int h = d >> BSH;
        int pos = offs[h] + (int)lp16[e];
        bedges[pos] = ((unsigned int)src[e] << BSH) | (unsigned int)(d & ((1 << BSH) - 1));
    }
}

// Block = bucket (<=256 nodes), 1024 threads: LDS histogram -> rowptr, dinv;
// place srcs into csr_src. (1024 thr: 391 blocks is only 1.5/CU; more threads
// per block halves the per-thread serial gather->atomic chain.)
__global__ __launch_bounds__(1024) void k_bucket_csr(const unsigned int* __restrict__ bedges,
                             const int* __restrict__ bucket_base,
                             int* __restrict__ rowptr, float* __restrict__ dinv,
                             int* __restrict__ csr_src, int N) {
    __shared__ int hist[256];
    __shared__ int sc[256];
    __shared__ int cur[256];
    int t = threadIdx.x;   // 0..1023
    int b = blockIdx.x;
    int base = bucket_base[b];
    int end = bucket_base[b + 1];
    if (t < 256) hist[t] = 0;
    __syncthreads();
    for (int i = base + t; i < end; i += TCSR)
        atomicAdd(&hist[bedges[i] & 255], 1);
    __syncthreads();
    int c = 0;
    if (t < 256) { c = hist[t]; sc[t] = c; }
    __syncthreads();
    for (int off = 1; off < 256; off <<= 1) {
        int u = (t >= off && t < 256) ? sc[t - off] : 0;
        __syncthreads();
        if (t < 256) sc[t] += u;
        __syncthreads();
    }
    if (t < 256) {
        int excl = sc[t] - c;
        int node = (b << BSH) + t;
        if (node < N) {
            rowptr[node] = base + excl;
            dinv[node] = (float)(1.0 / sqrt((double)(c + 1)));
        }
        cur[t] = excl;
    }
    __syncthreads();
    for (int i = base + t; i < end; i += TCSR) {
        unsigned int u = bedges[i];
        int ln = (int)(u & 255);
        int p = atomicAdd(&cur[ln], 1);
        csr_src[base + p] = (int)(u >> BSH);
    }
}

// GEMM1: 4 sub-lanes per row (interleaved k4 = q+4i), shfl_xor combine.
// Bank-clean: Wt word bank = (4q+16i) mod 32, distinct per q. 1563 blocks.
__global__ __launch_bounds__(256) void k_gemm1(const float* __restrict__ X,
                        const float* __restrict__ W,
                        const float* __restrict__ dinv, unsigned short* __restrict__ H, int N) {
    __shared__ float Wt[16 * 128];   // Wt[j][k] = W[k][j]
    int t = threadIdx.x;
    for (int i = t; i < 16 * 128; i += THREADS) {
        int j = i >> 7, k = i & 127;
        Wt[i] = W[k * 16 + j];
    }
    __syncthreads();
    int q = t & 3;                   // k sub-lane
    int row = blockIdx.x * 64 + (t >> 2);
    if (row >= N) return;
    const float4* xr = (const float4*)(X + (size_t)row * 128);
    float acc[16];
#pragma unroll
    for (int j = 0; j < 16; ++j) acc[j] = 0.0f;
#pragma unroll
    for (int i = 0; i < 8; ++i) {
        int k4 = q + 4 * i;
        float4 xv = xr[k4];
#pragma unroll
        for (int j = 0; j < 16; ++j) {
            const float4 wv = *(const float4*)&Wt[j * 128 + k4 * 4];
            acc[j] += xv.x * wv.x + xv.y * wv.y + xv.z * wv.z + xv.w * wv.w;
        }
    }
    // combine 4 k-slices (lanes 4r..4r+3)
#pragma unroll
    for (int j = 0; j < 16; ++j) {
        acc[j] += __shfl_xor(acc[j], 1);
        acc[j] += __shfl_xor(acc[j], 2);
    }
    if (q == 0) {
        float di = dinv[row];
        uint4 oa, ob;
        oa.x = pk2bf(acc[0] * di, acc[1] * di);
        oa.y = pk2bf(acc[2] * di, acc[3] * di);
        oa.z = pk2bf(acc[4] * di, acc[5] * di);
        oa.w = pk2bf(acc[6] * di, acc[7] * di);
        ob.x = pk2bf(acc[8] * di, acc[9] * di);
        ob.y = pk2bf(acc[10] * di, acc[11] * di);
        ob.z = pk2bf(acc[12] * di, acc[13] * di);
        ob.w = pk2bf(acc[14] * di, acc[15] * di);
        uint4* outr = (uint4*)(H + (size_t)row * 16);
        outr[0] = oa;
        outr[1] = ob;
    }
}

// Pull from bf16 table: 8 features per lane (16B gathers), S-way edge split
// per node (strided), partials combined via shfl_xor. Group = LPN*S lanes.
// t = dinv[n]*(sum_{e->n} Hb[src] + Hb[n])
// MODE 1: bf16 out = relu(t+b)*dinv (L1 out, pre-scaled for next pull)
// MODE 2: bf16 out = t              (L2 pre-GEMM aggregate)
// MODE 3: pooled: atomically accumulate t into gsums[batch[n]*32+f]
//         (bias deferred to head: mean(x+b) = mean(x)+b)
template<int F, int MODE, int S>
__global__ __launch_bounds__(256) void k_pull(
        const int* __restrict__ rowptr, const int* __restrict__ csr_src,
        const float* __restrict__ dinv, const unsigned short* __restrict__ Hb,
        const float* __restrict__ bias, void* __restrict__ outp,
        const int* __restrict__ batch, float* __restrict__ gsums,
        int N, int G) {
    const int LPN = F / 8;           // feature lanes per node
    const int GRP = LPN * S;         // lanes per node (8 for both configs)
    const int NPB = THREADS / GRP;   // nodes per block
    int t = threadIdx.x;
    int idx = t % GRP;
    int fl = idx % LPN;              // feature sub-lane (adjacent lanes share edge)
    int s  = idx / LPN;              // edge split index
    int fo = fl * 8;
    int node = blockIdx.x * NPB + t / GRP;

    float acc[8] = {0.f, 0.f, 0.f, 0.f, 0.f, 0.f, 0.f, 0.f};
    if (node < N) {
        int beg = rowptr[node], end = rowptr[node + 1];
        int i = beg + s;
        for (; i + 3 * S < end; i += 4 * S) {
            int s0 = csr_src[i];
            int s1 = csr_src[i + S];
            int s2 = csr_src[i + 2 * S];
            int s3 = csr_src[i + 3 * S];
            uint4 g0 = *(const uint4*)(Hb + (size_t)s0 * F + fo);
            uint4 g1 = *(const uint4*)(Hb + (size_t)s1 * F + fo);
            uint4 g2 = *(const uint4*)(Hb + (size_t)s2 * F + fo);
            uint4 g3 = *(const uint4*)(Hb + (size_t)s3 * F + fo);
            float f0[8], f1[8], f2[8], f3[8];
            unpk8(g0, f0); unpk8(g1, f1); unpk8(g2, f2); unpk8(g3, f3);
#pragma unroll
            for (int j = 0; j < 8; ++j) acc[j] += (f0[j] + f1[j]) + (f2[j] + f3[j]);
        }
        for (; i < end; i += S) {
            int sv = csr_src[i];
            uint4 g = *(const uint4*)(Hb + (size_t)sv * F + fo);
            float f[8];
            unpk8(g, f);
#pragma unroll
            for (int j = 0; j < 8; ++j) acc[j] += f[j];
        }
    }
    // combine S edge-split partials (groups of GRP lanes, GRP | 64)
#pragma unroll
    for (int j = 0; j < 8; ++j) {
        if (S >= 2) acc[j] += __shfl_xor(acc[j], LPN);
        if (S >= 4) acc[j] += __shfl_xor(acc[j], 2 * LPN);
    }

    if constexpr (MODE == 3) {
        // fused global_mean_pool accumulate (batch is sorted: block spans few graphs)
        __shared__ float lsum[4][32];
        __shared__ int g0s;
        for (int z = t; z < 4 * 32; z += THREADS) ((float*)lsum)[z] = 0.0f;
        if (t == 0) g0s = batch[blockIdx.x * NPB];
        __syncthreads();
        int g0 = g0s;
        if (node < N && s == 0) {
            uint4 gs = *(const uint4*)(Hb + (size_t)node * F + fo);
            float sf[8];
            unpk8(gs, sf);
            float di = dinv[node];
            int g = batch[node];
            int r = g - g0;
            if ((unsigned)r < 4u) {
#pragma unroll
                for (int j = 0; j < 8; ++j)
                    atomicAdd(&lsum[r][fo + j], di * (acc[j] + sf[j]));
            } else {  // safety fallback (tiny graphs / unsorted batch)
#pragma unroll
                for (int j = 0; j < 8; ++j)
                    atomicAdd(&gsums[(size_t)g * 32 + fo + j], di * (acc[j] + sf[j]));
            }
        }
        __syncthreads();
        if (t < 128) {
            int r = t >> 5, f = t & 31;
            int g = g0 + r;
            float v = lsum[r][f];
            if (g < G && v != 0.0f) atomicAdd(&gsums[(size_t)g * 32 + f], v);
        }
    } else {
        if (node < N && s == 0) {
            uint4 gs = *(const uint4*)(Hb + (size_t)node * F + fo);
            float sf[8];
            unpk8(gs, sf);
            float di = dinv[node];
            float tv[8];
#pragma unroll
            for (int j = 0; j < 8; ++j) tv[j] = di * (acc[j] + sf[j]);
            if constexpr (MODE == 1) {
                float w[8];
#pragma unroll
                for (int j = 0; j < 8; ++j) w[j] = fmaxf(tv[j] + bias[fo + j], 0.0f) * di;
                uint4 st;
                st.x = pk2bf(w[0], w[1]); st.y = pk2bf(w[2], w[3]);
                st.z = pk2bf(w[4], w[5]); st.w = pk2bf(w[6], w[7]);
                *(uint4*)((unsigned short*)outp + (size_t)node * F + fo) = st;
            } else {  // MODE 2: bf16 aggregate (same RNE quantization mlp applied)
                uint4 st;
                st.x = pk2bf(tv[0], tv[1]); st.y = pk2bf(tv[2], tv[3]);
                st.z = pk2bf(tv[4], tv[5]); st.w = pk2bf(tv[6], tv[7]);
                *(uint4*)((unsigned short*)outp + (size_t)node * F + fo) = st;
            }
        }
    }
}

// MFMA MLP: wave handles 16 nodes. Swapped operands keep node on lane&15:
//   GEMM-A: D1 = W2^T(A) x P2^T(B), K=16 padded to 32 (zeros pair with zeros).
//   relu(D1 + b2) -> bf16-pair dwords in wave-local LDS (aTd[j/2][node]).
//   GEMM-B: D2 = W3^T(A) x a^T(B from LDS), K=64 (2 k-steps), M=32 (2 tiles).
// C/D layout (verified): col=lane&15, row=(lane>>4)*4+reg.
// P2b is bf16: B-frag loads are direct 16B reinterprets (no conversion).
__global__ __launch_bounds__(256) void k_mlp(const unsigned short* __restrict__ P2b,
                      const float* __restrict__ W2, const float* __restrict__ b2,
                      const float* __restrict__ W3, const float* __restrict__ dinv,
                      unsigned short* __restrict__ Hb3, int N) {
    __shared__ unsigned int aTd[4][32][17];  // [wave][j/2][node] bf16-pair
    int t = threadIdx.x;
    int w = t >> 6;          // wave 0..3
    int l = t & 63;
    int g = l >> 4;          // lane group 0..3
    int c = l & 15;          // node / row-col index
    int node = blockIdx.x * 64 + w * 16 + c;
    bool nv = node < N;
    int cn = nv ? node : 0;

    // A-frags: W2^T tiles (row j=16*mi+c, k=8g+e; k>=16 -> 0)
    short8 w2f[4];
#pragma unroll
    for (int mi = 0; mi < 4; ++mi) {
        short8 f = {0, 0, 0, 0, 0, 0, 0, 0};
        if (g < 2) {
            int j = 16 * mi + c;
#pragma unroll
            for (int e = 0; e < 8; ++e)
                f[e] = (short)f2bf(W2[(8 * g + e) * 64 + j]);
        }
        w2f[mi] = f;
    }
    // A-frags: W3^T (row m=16*mt+c, k j=32*kt+8g+e)
    short8 w3f[2][2];
#pragma unroll
    for (int mt = 0; mt < 2; ++mt)
#pragma unroll
        for (int kt = 0; kt < 2; ++kt) {
            short8 f;
#pragma unroll
            for (int e = 0; e < 8; ++e)
                f[e] = (short)f2bf(W3[(32 * kt + 8 * g + e) * 32 + 16 * mt + c]);
            w3f[mt][kt] = f;
        }
    // b2 for this lane's C/D rows: j = 16*mi + 4*g + r
    float b2v[16];
#pragma unroll
    for (int mi = 0; mi < 4; ++mi)
#pragma unroll
        for (int r = 0; r < 4; ++r)
            b2v[4 * mi + r] = b2[16 * mi + 4 * g + r];

    // B-frag: P2b^T (col=node(c), k=8g+e; k>=16 -> 0); direct bf16 reinterpret
    short8 pf = {0, 0, 0, 0, 0, 0, 0, 0};
    if (g < 2) {
        pf = *(const short8*)(P2b + (size_t)cn * 16 + 8 * g);
    }

    // GEMM-A: acc1[mi] = W2^T[16mi..] x P2^T  (D1[j][node])
    f32x4 zero = {0.f, 0.f, 0.f, 0.f};
    f32x4 acc1[4];
#pragma unroll
    for (int mi = 0; mi < 4; ++mi)
        acc1[mi] = __builtin_amdgcn_mfma_f32_16x16x32_bf16(w2f[mi], pf, zero, 0, 0, 0);

    // relu + bias -> LDS as bf16-pair dwords: j-pair (16mi+4g, +1) -> row 8mi+2g
#pragma unroll
    for (int mi = 0; mi < 4; ++mi) {
        float a0 = fmaxf(acc1[mi][0] + b2v[4 * mi + 0], 0.f);
        float a1 = fmaxf(acc1[mi][1] + b2v[4 * mi + 1], 0.f);
        float a2 = fmaxf(acc1[mi][2] + b2v[4 * mi + 2], 0.f);
        float a3 = fmaxf(acc1[mi][3] + b2v[4 * mi + 3], 0.f);
        aTd[w][8 * mi + 2 * g][c]     = pk2bf(a0, a1);
        aTd[w][8 * mi + 2 * g + 1][c] = pk2bf(a2, a3);
    }
    __syncthreads();  // waves touch only their own slice; barrier for LDS visibility

    // B-frags: a^T from LDS; elem pair (2i,2i+1) <-> j = 32kt+8g+2i -> row 16kt+4g+i
    short8 bfr[2];
#pragma unroll
    for (int kt = 0; kt < 2; ++kt) {
        short8 f;
#pragma unroll
        for (int i = 0; i < 4; ++i) {
            unsigned int d = aTd[w][16 * kt + 4 * g + i][c];
            f[2 * i]     = (short)(d & 0xffffu);
            f[2 * i + 1] = (short)(d >> 16);
        }
        bfr[kt] = f;
    }

    // GEMM-B: acc2[mt] = sum_kt W3^T x a^T  (D2[m][node])
    f32x4 acc2[2] = {{0.f, 0.f, 0.f, 0.f}, {0.f, 0.f, 0.f, 0.f}};
#pragma unroll
    for (int mt = 0; mt < 2; ++mt)
#pragma unroll
        for (int kt = 0; kt < 2; ++kt)
            acc2[mt] = __builtin_amdgcn_mfma_f32_16x16x32_bf16(w3f[mt][kt], bfr[kt], acc2[mt], 0, 0, 0);

    // store: m = 16mt + 4g + r, Hb3[node][m] bf16 (dword pairs, 8B-aligned)
    if (nv) {
        float di = dinv[node];
        unsigned short* o = Hb3 + (size_t)node * 32;
#pragma unroll
        for (int mt = 0; mt < 2; ++mt) {
            *(unsigned int*)(o + 16 * mt + 4 * g)     = pk2bf(acc2[mt][0] * di, acc2[mt][1] * di);
            *(unsigned int*)(o + 16 * mt + 4 * g + 2) = pk2bf(acc2[mt][2] * di, acc2[mt][3] * di);
        }
    }
}

// Head: cnt via binary search; pooled = sums/cnt + b3; a=relu(pooled@Wa+ba);
// out=tanh(a@Wo+bo)
__global__ void k_head(const float* __restrict__ sums, const int* __restrict__ batch, int N,
                       const float* __restrict__ b3,
                       const float* __restrict__ Wa, const float* __restrict__ ba,
                       const float* __restrict__ Wo, const float* __restrict__ bo,
                       float* __restrict__ out) {
    int g = blockIdx.x;
    int j = threadIdx.x;  // 64 threads
    int lo = 0, hi = N;
    while (lo < hi) { int m = (lo + hi) >> 1; if (batch[m] < g) lo = m + 1; else hi = m; }
    int start = lo;
    lo = start; hi = N;
    while (lo < hi) { int m = (lo + hi) >> 1; if (batch[m] < g + 1) lo = m + 1; else hi = m; }
    int cnt = lo - start;
    float inv = 1.0f / (float)(cnt > 0 ? cnt : 1);

    __shared__ float p[32];
    __shared__ float a[64];
    if (j < 32) p[j] = sums[g * 32 + j] * inv + b3[j];
    __syncthreads();
    float acc = ba[j];
#pragma unroll
    for (int k = 0; k < 32; ++k) acc += p[k] * Wa[k * 64 + j];
    a[j] = fmaxf(acc, 0.0f);
    __syncthreads();
    if (j < 32) {
        float acc2 = bo[j];
#pragma unroll
        for (int k = 0; k < 64; ++k) acc2 += a[k] * Wo[k * 32 + j];
        out[g * 32 + j] = tanhf(acc2);
    }
}

static inline int cdiv(long long a, int b) { return (int)((a + b - 1) / b); }
static inline size_t align256(size_t x) { return (x + 255) & ~(size_t)255; }

extern "C" void kernel_launch(void* const* d_in, const int* in_sizes, int n_in,
                              void* d_out, int out_size, void* d_ws, size_t ws_size,
                              hipStream_t stream) {
    const float* x     = (const float*)d_in[0];
    const int*   edge  = (const int*)d_in[1];
    const int*   batch = (const int*)d_in[2];
    const float* W1 = (const float*)d_in[3];  const float* b1 = (const float*)d_in[4];
    const float* W2 = (const float*)d_in[5];  const float* b2 = (const float*)d_in[6];
    const float* W3 = (const float*)d_in[7];  const float* b3 = (const float*)d_in[8];
    const float* Wa = (const float*)d_in[9];  const float* ba = (const float*)d_in[10];
    const float* Wo = (const float*)d_in[11]; const float* bo = (const float*)d_in[12];

    const int E = in_sizes[1] / 2;
    const int N = in_sizes[2];
    const int G = 64;
    const int NB = cdiv(N, 1 << BSH);     // 391
    const int NCH = cdiv(E, CH_E);        // 782

    const int* srcp = edge;
    const int* dstp = edge + E;

    // Workspace
    char* base = (char*)d_ws;
    size_t off = 0;
    float* dinv   = (float*)(base + off); off = align256(off + sizeof(float) * N);
    unsigned short* lp16 = (unsigned short*)(base + off); off = align256(off + sizeof(short) * E);
    int* cnt_mat  = (int*)(base + off); off = align256(off + sizeof(int) * (size_t)NB * NCH);
    int* offs_mat = (int*)(base + off); off = align256(off + sizeof(int) * (size_t)NB * NCH);
    int* btot     = (int*)(base + off); off = align256(off + sizeof(int) * (NB + 1));
    int* bbase    = (int*)(base + off); off = align256(off + sizeof(int) * (NB + 1));
    unsigned int* bedges = (unsigned int*)(base + off); off = align256(off + sizeof(int) * E);
    int* rowptr   = (int*)(base + off); off = align256(off + sizeof(int) * (N + 1));
    int* csr_src  = (int*)(base + off); off = align256(off + sizeof(int) * E);
    unsigned short* Hb1 = (unsigned short*)(base + off); off = align256(off + sizeof(short) * (size_t)N * 16);
    unsigned short* Hb2 = (unsigned short*)(base + off); off = align256(off + sizeof(short) * (size_t)N * 16);
    unsigned short* P2b = (unsigned short*)(base + off); off = align256(off + sizeof(short) * (size_t)N * 16);
    unsigned short* Hb3 = (unsigned short*)(base + off); off = align256(off + sizeof(short) * (size_t)N * 32);
    float* sums   = (float*)(base + off); off = align256(off + sizeof(float) * G * 32);

    // ---- Atomic-free binning -> bucket-sorted bedges ----
    k_countA<<<NCH, THREADS, 0, stream>>>(dstp, lp16, cnt_mat, E, NB, NCH);
    k_sumK1<<<NB, THREADS, 0, stream>>>(cnt_mat, btot, NCH);
    k_scanK2<<<1, MAXNB, 0, stream>>>(btot, bbase, rowptr, sums, NB, E, N, G * 32);
    k_scanK3<<<NB, THREADS, 0, stream>>>(cnt_mat, bbase, offs_mat, NCH);
    k_scatter2<<<NCH, THREADS, 0, stream>>>(srcp, dstp, lp16, offs_mat, bedges, E, NB, NCH);

    // ---- CSR (rowptr, csr_src, dinv) from bucket-sorted edges ----
    k_bucket_csr<<<NB, TCSR, 0, stream>>>(bedges, bbase, rowptr, dinv, csr_src, N);

    // ---- Layer 1: Hb1 = bf16((x@W1)*dinv); pull16 -> Hb2 = bf16(relu(.+b1)*dinv) ----
    k_gemm1<<<cdiv(N, 64), THREADS, 0, stream>>>(x, W1, dinv, Hb1, N);
    k_pull<16, 1, 4><<<cdiv(N, 32), THREADS, 0, stream>>>(rowptr, csr_src, dinv, Hb1, b1, Hb2,
                                                          nullptr, nullptr, N, G);

    // ---- Layer 2 aggregate at input width: P2b = bf16(pull16(Hb2)) ----
    k_pull<16, 2, 4><<<cdiv(N, 32), THREADS, 0, stream>>>(rowptr, csr_src, dinv, Hb2, nullptr, P2b,
                                                          nullptr, nullptr, N, G);

    // ---- Fused node MLP (MFMA): Hb3 = bf16((relu(P2b@W2+b2)@W3)*dinv) ----
    k_mlp<<<cdiv(N, 64), THREADS, 0, stream>>>(P2b, W2, b2, W3, dinv, Hb3, N);

    // ---- Layer 3 aggregate fused with pooling: sums[g] += dinv*(agg+self) ----
    k_pull<32, 3, 2><<<cdiv(N, 32), THREADS, 0, stream>>>(rowptr, csr_src, dinv, Hb3, nullptr,
                                                          nullptr, batch, sums, N, G);

    // ---- Head (adds deferred b3) ----
    k_head<<<G, 64, 0, stream>>>(sums, batch, N, b3, Wa, ba, Wo, bo, (float*)d_out);
}

// Round 9
// 282.276 us; speedup vs baseline: 3.7831x; 1.0892x over previous
//
#include <hip/hip_runtime.h>
#include <hip/hip_bf16.h>
#include <math.h>

// ActorGNN R18: R17 + scattered-write fixes (the ~16x write-amplification in
// scatter2 / bucket_csr): chunk-local counting sort in LDS -> coalesced run
// writes (scatter2); LDS-staged csr_src permutation -> coalesced sweep
// (bucket_csr, CAP 8704 + fallback). Numerically identical.
// N=100000, E=3200000, G=64.

#define THREADS 256
#define TCSR 1024             // threads for k_bucket_csr
#define BSH 8                 // bucket shift: bucket = dst>>8 (<=256 nodes each)
#define MAXNB 512             // LDS histogram capacity (N <= 131072)
#define CH_E 4096             // edges per chunk in binning passes
#define CPT 8                 // chunks per thread in k_scanK3 (NCH <= 2048)
#define CSR_CAP 8704          // LDS staging cap for one bucket's edges (avg 8192 + 4sigma)

typedef __attribute__((ext_vector_type(8))) short short8;
typedef __attribute__((ext_vector_type(4))) float f32x4;

// ---- bf16 helpers ----
__device__ inline unsigned short f2bf(float f) {
    unsigned int u = __float_as_uint(f);
    return (unsigned short)((u + 0x7fffu + ((u >> 16) & 1u)) >> 16);  // RNE
}
__device__ inline unsigned int pk2bf(float a, float b) {
    return (unsigned int)f2bf(a) | ((unsigned int)f2bf(b) << 16);
}
__device__ inline float bflo(unsigned int u) { return __uint_as_float(u << 16); }
__device__ inline float bfhi(unsigned int u) { return __uint_as_float(u & 0xffff0000u); }
__device__ inline void unpk8(const uint4 u, float* f) {
    f[0] = bflo(u.x); f[1] = bfhi(u.x); f[2] = bflo(u.y); f[3] = bfhi(u.y);
    f[4] = bflo(u.z); f[5] = bfhi(u.z); f[6] = bflo(u.w); f[7] = bfhi(u.w);
}

// ---- Atomic-free binning: pass A counts + records local position ----
__global__ void k_countA(const int* __restrict__ dst, unsigned short* __restrict__ lp16,
                         int* __restrict__ cnt_mat, int E, int NB, int NCH) {
    __shared__ int hist[MAXNB];
    int t = threadIdx.x, chunk = blockIdx.x;
    for (int h = t; h < NB; h += THREADS) hist[h] = 0;
    __syncthreads();
    int e0 = chunk * CH_E, e1 = min(E, e0 + CH_E);
    for (int e = e0 + t; e < e1; e += THREADS) {
        int h = dst[e] >> BSH;
        int lp = atomicAdd(&hist[h], 1);
        lp16[e] = (unsigned short)lp;
    }
    __syncthreads();
    for (int h = t; h < NB; h += THREADS) cnt_mat[(size_t)h * NCH + chunk] = hist[h];
}

// K1: bucket totals
__global__ void k_sumK1(const int* __restrict__ cnt_mat, int* __restrict__ bucket_tot, int NCH) {
    __shared__ int red[THREADS];
    int b = blockIdx.x, t = threadIdx.x;
    int s = 0;
    for (int c = t; c < NCH; c += THREADS) s += cnt_mat[(size_t)b * NCH + c];
    red[t] = s;
    __syncthreads();
    for (int off = THREADS / 2; off > 0; off >>= 1) {
        if (t < off) red[t] += red[t + off];
        __syncthreads();
    }
    if (t == 0) bucket_tot[b] = red[0];
}

// K2: single block exclusive scan of NB bucket totals -> bucket_base; [NB]=E.
// Also sets rowptr[N]=E and zeroes sums (independent side work, saves a launch).
__global__ void k_scanK2(const int* __restrict__ bucket_tot, int* __restrict__ bucket_base,
                         int* __restrict__ rowptr, float* __restrict__ sums,
                         int NB, int E, int N, int GS) {
    __shared__ int sh[MAXNB];
    int t = threadIdx.x;  // 512
    for (int i = t; i < GS; i += MAXNB) sums[i] = 0.0f;
    int v = (t < NB) ? bucket_tot[t] : 0;
    sh[t] = v;
    __syncthreads();
    for (int off = 1; off < MAXNB; off <<= 1) {
        int u = (t >= off) ? sh[t - off] : 0;
        __syncthreads();
        sh[t] += u;
        __syncthreads();
    }
    if (t < NB) bucket_base[t] = sh[t] - v;
    if (t == 0) { bucket_base[NB] = E; rowptr[N] = E; }
}

// K3: per-bucket exclusive scan over chunks + bucket base -> offs_mat
__global__ void k_scanK3(const int* __restrict__ cnt_mat, const int* __restrict__ bucket_base,
                         int* __restrict__ offs_mat, int NCH) {
    __shared__ int sh[THREADS];
    int b = blockIdx.x, t = threadIdx.x;
    int c0 = t * CPT;
    int v[CPT];
    int s = 0;
#pragma unroll
    for (int k = 0; k < CPT; ++k) {
        int c = c0 + k;
        v[k] = (c < NCH) ? cnt_mat[(size_t)b * NCH + c] : 0;
        s += v[k];
    }
    sh[t] = s;
    __syncthreads();
    for (int off = 1; off < THREADS; off <<= 1) {
        int u = (t >= off) ? sh[t - off] : 0;
        __syncthreads();
        sh[t] += u;
        __syncthreads();
    }
    int run = bucket_base[b] + sh[t] - s;
#pragma unroll
    for (int k = 0; k < CPT; ++k) {
        int c = c0 + k;
        if (c < NCH) { offs_mat[(size_t)b * NCH + c] = run; run += v[k]; }
    }
}

// Pass B: chunk-local counting sort in LDS, then coalesced run writes.
// Slot s = excl[h]+lp (chunk-local sorted order); gpos[s] = offs[h]+lp.
// Consecutive s within a bucket -> consecutive global addresses.
__global__ __launch_bounds__(256) void k_scatter2(
        const int* __restrict__ src, const int* __restrict__ dst,
        const unsigned short* __restrict__ lp16,
        const int* __restrict__ cnt_mat, const int* __restrict__ offs_mat,
        unsigned int* __restrict__ bedges, int E, int NB, int NCH) {
    __shared__ int offs[MAXNB];
    __shared__ int excl[MAXNB];        // exclusive scan of chunk hist
    __shared__ unsigned int wbuf[CH_E];
    __shared__ int gbuf[CH_E];
    int t = threadIdx.x, chunk = blockIdx.x;
    // load chunk counts (2 slots/thread, NB<=512) and scan them
    int c0 = (t < NB) ? cnt_mat[(size_t)t * NCH + chunk] : 0;
    int c1 = (t + 256 < NB) ? cnt_mat[(size_t)(t + 256) * NCH + chunk] : 0;
    if (t < NB) offs[t] = offs_mat[(size_t)t * NCH + chunk];
    if (t + 256 < NB) offs[t + 256] = offs_mat[(size_t)(t + 256) * NCH + chunk];
    excl[t] = c0;
    excl[t + 256] = c1;
    __syncthreads();
    for (int off = 1; off < MAXNB; off <<= 1) {
        int a = (t >= off) ? excl[t - off] : 0;
        int b = (t + 256 >= off) ? excl[t + 256 - off] : 0;
        __syncthreads();
        excl[t] += a;
        excl[t + 256] += b;
        __syncthreads();
    }
    // convert inclusive -> exclusive (per-slot, using saved counts)
    excl[t] -= c0;
    excl[t + 256] -= c1;
    __syncthreads();
    int e0 = chunk * CH_E, e1 = min(E, e0 + CH_E);
    int len = e1 - e0;
    for (int e = e0 + t; e < e1; e += THREADS) {
        int d = dst[e];
        int h = d >> BSH;
        int lp = (int)lp16[e];
        int s = excl[h] + lp;
        wbuf[s] = ((unsigned int)src[e] << BSH) | (unsigned int)(d & ((1 << BSH) - 1));
        gbuf[s] = offs[h] + lp;
    }
    __syncthreads();
    for (int s = t; s < len; s += THREADS)
        bedges[gbuf[s]] = wbuf[s];
}

// Block = bucket (<=256 nodes), 1024 threads: LDS histogram -> rowptr, dinv;
// stage csr_src permutation in LDS, write out coalesced (CAP fallback: global).
__global__ __launch_bounds__(1024) void k_bucket_csr(const unsigned int* __restrict__ bedges,
                             const int* __restrict__ bucket_base,
                             int* __restrict__ rowptr, float* __restrict__ dinv,
                             int* __restrict__ csr_src, int N) {
    __shared__ int hist[256];
    __shared__ int sc[256];
    __shared__ int cur[256];
    __shared__ int ssrc[CSR_CAP];
    int t = threadIdx.x;   // 0..1023
    int b = blockIdx.x;
    int base = bucket_base[b];
    int end = bucket_base[b + 1];
    int tot = end - base;
    bool lds_ok = tot <= CSR_CAP;
    if (t < 256) hist[t] = 0;
    __syncthreads();
    for (int i = base + t; i < end; i += TCSR)
        atomicAdd(&hist[bedges[i] & 255], 1);
    __syncthreads();
    int c = 0;
    if (t < 256) { c = hist[t]; sc[t] = c; }
    __syncthreads();
    for (int off = 1; off < 256; off <<= 1) {
        int u = (t >= off && t < 256) ? sc[t - off] : 0;
        __syncthreads();
        if (t < 256) sc[t] += u;
        __syncthreads();
    }
    if (t < 256) {
        int excl = sc[t] - c;
        int node = (b << BSH) + t;
        if (node < N) {
            rowptr[node] = base + excl;
            dinv[node] = (float)(1.0 / sqrt((double)(c + 1)));
        }
        cur[t] = excl;
    }
    __syncthreads();
    if (lds_ok) {
        for (int i = base + t; i < end; i += TCSR) {
            unsigned int u = bedges[i];
            int ln = (int)(u & 255);
            int p = atomicAdd(&cur[ln], 1);
            ssrc[p] = (int)(u >> BSH);
        }
        __syncthreads();
        for (int j = t; j < tot; j += TCSR)
            csr_src[base + j] = ssrc[j];
    } else {
        for (int i = base + t; i < end; i += TCSR) {
            unsigned int u = bedges[i];
            int ln = (int)(u & 255);
            int p = atomicAdd(&cur[ln], 1);
            csr_src[base + p] = (int)(u >> BSH);
        }
    }
}

// GEMM1: 4 sub-lanes per row (interleaved k4 = q+4i), shfl_xor combine.
__global__ __launch_bounds__(256) void k_gemm1(const float* __restrict__ X,
                        const float* __restrict__ W,
                        const float* __restrict__ dinv, unsigned short* __restrict__ H, int N) {
    __shared__ float Wt[16 * 128];   // Wt[j][k] = W[k][j]
    int t = threadIdx.x;
    for (int i = t; i < 16 * 128; i += THREADS) {
        int j = i >> 7, k = i & 127;
        Wt[i] = W[k * 16 + j];
    }
    __syncthreads();
    int q = t & 3;                   // k sub-lane
    int row = blockIdx.x * 64 + (t >> 2);
    if (row >= N) return;
    const float4* xr = (const float4*)(X + (size_t)row * 128);
    float acc[16];
#pragma unroll
    for (int j = 0; j < 16; ++j) acc[j] = 0.0f;
#pragma unroll
    for (int i = 0; i < 8; ++i) {
        int k4 = q + 4 * i;
        float4 xv = xr[k4];
#pragma unroll
        for (int j = 0; j < 16; ++j) {
            const float4 wv = *(const float4*)&Wt[j * 128 + k4 * 4];
            acc[j] += xv.x * wv.x + xv.y * wv.y + xv.z * wv.z + xv.w * wv.w;
        }
    }
#pragma unroll
    for (int j = 0; j < 16; ++j) {
        acc[j] += __shfl_xor(acc[j], 1);
        acc[j] += __shfl_xor(acc[j], 2);
    }
    if (q == 0) {
        float di = dinv[row];
        uint4 oa, ob;
        oa.x = pk2bf(acc[0] * di, acc[1] * di);
        oa.y = pk2bf(acc[2] * di, acc[3] * di);
        oa.z = pk2bf(acc[4] * di, acc[5] * di);
        oa.w = pk2bf(acc[6] * di, acc[7] * di);
        ob.x = pk2bf(acc[8] * di, acc[9] * di);
        ob.y = pk2bf(acc[10] * di, acc[11] * di);
        ob.z = pk2bf(acc[12] * di, acc[13] * di);
        ob.w = pk2bf(acc[14] * di, acc[15] * di);
        uint4* outr = (uint4*)(H + (size_t)row * 16);
        outr[0] = oa;
        outr[1] = ob;
    }
}

// Pull from bf16 table: 8 features per lane (16B gathers), S-way edge split
// per node (strided), partials combined via shfl_xor. Group = LPN*S lanes.
// t = dinv[n]*(sum_{e->n} Hb[src] + Hb[n])
// MODE 1: bf16 out = relu(t+b)*dinv (L1 out, pre-scaled for next pull)
// MODE 2: bf16 out = t              (L2 pre-GEMM aggregate)
// MODE 3: pooled: atomically accumulate t into gsums[batch[n]*32+f]
//         (bias deferred to head: mean(x+b) = mean(x)+b)
template<int F, int MODE, int S>
__global__ __launch_bounds__(256) void k_pull(
        const int* __restrict__ rowptr, const int* __restrict__ csr_src,
        const float* __restrict__ dinv, const unsigned short* __restrict__ Hb,
        const float* __restrict__ bias, void* __restrict__ outp,
        const int* __restrict__ batch, float* __restrict__ gsums,
        int N, int G) {
    const int LPN = F / 8;           // feature lanes per node
    const int GRP = LPN * S;         // lanes per node (8 for both configs)
    const int NPB = THREADS / GRP;   // nodes per block
    int t = threadIdx.x;
    int idx = t % GRP;
    int fl = idx % LPN;              // feature sub-lane (adjacent lanes share edge)
    int s  = idx / LPN;              // edge split index
    int fo = fl * 8;
    int node = blockIdx.x * NPB + t / GRP;

    float acc[8] = {0.f, 0.f, 0.f, 0.f, 0.f, 0.f, 0.f, 0.f};
    if (node < N) {
        int beg = rowptr[node], end = rowptr[node + 1];
        int i = beg + s;
        for (; i + 3 * S < end; i += 4 * S) {
            int s0 = csr_src[i];
            int s1 = csr_src[i + S];
            int s2 = csr_src[i + 2 * S];
            int s3 = csr_src[i + 3 * S];
            uint4 g0 = *(const uint4*)(Hb + (size_t)s0 * F + fo);
            uint4 g1 = *(const uint4*)(Hb + (size_t)s1 * F + fo);
            uint4 g2 = *(const uint4*)(Hb + (size_t)s2 * F + fo);
            uint4 g3 = *(const uint4*)(Hb + (size_t)s3 * F + fo);
            float f0[8], f1[8], f2[8], f3[8];
            unpk8(g0, f0); unpk8(g1, f1); unpk8(g2, f2); unpk8(g3, f3);
#pragma unroll
            for (int j = 0; j < 8; ++j) acc[j] += (f0[j] + f1[j]) + (f2[j] + f3[j]);
        }
        for (; i < end; i += S) {
            int sv = csr_src[i];
            uint4 g = *(const uint4*)(Hb + (size_t)sv * F + fo);
            float f[8];
            unpk8(g, f);
#pragma unroll
            for (int j = 0; j < 8; ++j) acc[j] += f[j];
        }
    }
    // combine S edge-split partials (groups of GRP lanes, GRP | 64)
#pragma unroll
    for (int j = 0; j < 8; ++j) {
        if (S >= 2) acc[j] += __shfl_xor(acc[j], LPN);
        if (S >= 4) acc[j] += __shfl_xor(acc[j], 2 * LPN);
    }

    if constexpr (MODE == 3) {
        // fused global_mean_pool accumulate (batch is sorted: block spans few graphs)
        __shared__ float lsum[4][32];
        __shared__ int g0s;
        for (int z = t; z < 4 * 32; z += THREADS) ((float*)lsum)[z] = 0.0f;
        if (t == 0) g0s = batch[blockIdx.x * NPB];
        __syncthreads();
        int g0 = g0s;
        if (node < N && s == 0) {
            uint4 gs = *(const uint4*)(Hb + (size_t)node * F + fo);
            float sf[8];
            unpk8(gs, sf);
            float di = dinv[node];
            int g = batch[node];
            int r = g - g0;
            if ((unsigned)r < 4u) {
#pragma unroll
                for (int j = 0; j < 8; ++j)
                    atomicAdd(&lsum[r][fo + j], di * (acc[j] + sf[j]));
            } else {  // safety fallback (tiny graphs / unsorted batch)
#pragma unroll
                for (int j = 0; j < 8; ++j)
                    atomicAdd(&gsums[(size_t)g * 32 + fo + j], di * (acc[j] + sf[j]));
            }
        }
        __syncthreads();
        if (t < 128) {
            int r = t >> 5, f = t & 31;
            int g = g0 + r;
            float v = lsum[r][f];
            if (g < G && v != 0.0f) atomicAdd(&gsums[(size_t)g * 32 + f], v);
        }
    } else {
        if (node < N && s == 0) {
            uint4 gs = *(const uint4*)(Hb + (size_t)node * F + fo);
            float sf[8];
            unpk8(gs, sf);
            float di = dinv[node];
            float tv[8];
#pragma unroll
            for (int j = 0; j < 8; ++j) tv[j] = di * (acc[j] + sf[j]);
            if constexpr (MODE == 1) {
                float w[8];
#pragma unroll
                for (int j = 0; j < 8; ++j) w[j] = fmaxf(tv[j] + bias[fo + j], 0.0f) * di;
                uint4 st;
                st.x = pk2bf(w[0], w[1]); st.y = pk2bf(w[2], w[3]);
                st.z = pk2bf(w[4], w[5]); st.w = pk2bf(w[6], w[7]);
                *(uint4*)((unsigned short*)outp + (size_t)node * F + fo) = st;
            } else {  // MODE 2: bf16 aggregate (same RNE quantization mlp applied)
                uint4 st;
                st.x = pk2bf(tv[0], tv[1]); st.y = pk2bf(tv[2], tv[3]);
                st.z = pk2bf(tv[4], tv[5]); st.w = pk2bf(tv[6], tv[7]);
                *(uint4*)((unsigned short*)outp + (size_t)node * F + fo) = st;
            }
        }
    }
}

// MFMA MLP: wave handles 16 nodes. Swapped operands keep node on lane&15:
//   GEMM-A: D1 = W2^T(A) x P2^T(B), K=16 padded to 32 (zeros pair with zeros).
//   relu(D1 + b2) -> bf16-pair dwords in wave-local LDS (aTd[j/2][node]).
//   GEMM-B: D2 = W3^T(A) x a^T(B from LDS), K=64 (2 k-steps), M=32 (2 tiles).
// C/D layout (verified): col=lane&15, row=(lane>>4)*4+reg.
// P2b is bf16: B-frag loads are direct 16B reinterprets (no conversion).
__global__ __launch_bounds__(256) void k_mlp(const unsigned short* __restrict__ P2b,
                      const float* __restrict__ W2, const float* __restrict__ b2,
                      const float* __restrict__ W3, const float* __restrict__ dinv,
                      unsigned short* __restrict__ Hb3, int N) {
    __shared__ unsigned int aTd[4][32][17];  // [wave][j/2][node] bf16-pair
    int t = threadIdx.x;
    int w = t >> 6;          // wave 0..3
    int l = t & 63;
    int g = l >> 4;          // lane group 0..3
    int c = l & 15;          // node / row-col index
    int node = blockIdx.x * 64 + w * 16 + c;
    bool nv = node < N;
    int cn = nv ? node : 0;

    // A-frags: W2^T tiles (row j=16*mi+c, k=8g+e; k>=16 -> 0)
    short8 w2f[4];
#pragma unroll
    for (int mi = 0; mi < 4; ++mi) {
        short8 f = {0, 0, 0, 0, 0, 0, 0, 0};
        if (g < 2) {
            int j = 16 * mi + c;
#pragma unroll
            for (int e = 0; e < 8; ++e)
                f[e] = (short)f2bf(W2[(8 * g + e) * 64 + j]);
        }
        w2f[mi] = f;
    }
    // A-frags: W3^T (row m=16*mt+c, k j=32*kt+8g+e)
    short8 w3f[2][2];
#pragma unroll
    for (int mt = 0; mt < 2; ++mt)
#pragma unroll
        for (int kt = 0; kt < 2; ++kt) {
            short8 f;
#pragma unroll
            for (int e = 0; e < 8; ++e)
                f[e] = (short)f2bf(W3[(32 * kt + 8 * g + e) * 32 + 16 * mt + c]);
            w3f[mt][kt] = f;
        }
    // b2 for this lane's C/D rows: j = 16*mi + 4*g + r
    float b2v[16];
#pragma unroll
    for (int mi = 0; mi < 4; ++mi)
#pragma unroll
        for (int r = 0; r < 4; ++r)
            b2v[4 * mi + r] = b2[16 * mi + 4 * g + r];

    // B-frag: P2b^T (col=node(c), k=8g+e; k>=16 -> 0); direct bf16 reinterpret
    short8 pf = {0, 0, 0, 0, 0, 0, 0, 0};
    if (g < 2) {
        pf = *(const short8*)(P2b + (size_t)cn * 16 + 8 * g);
    }

    // GEMM-A: acc1[mi] = W2^T[16mi..] x P2^T  (D1[j][node])
    f32x4 zero = {0.f, 0.f, 0.f, 0.f};
    f32x4 acc1[4];
#pragma unroll
    for (int mi = 0; mi < 4; ++mi)
        acc1[mi] = __builtin_amdgcn_mfma_f32_16x16x32_bf16(w2f[mi], pf, zero, 0, 0, 0);

    // relu + bias -> LDS as bf16-pair dwords: j-pair (16mi+4g, +1) -> row 8mi+2g
#pragma unroll
    for (int mi = 0; mi < 4; ++mi) {
        float a0 = fmaxf(acc1[mi][0] + b2v[4 * mi + 0], 0.f);
        float a1 = fmaxf(acc1[mi][1] + b2v[4 * mi + 1], 0.f);
        float a2 = fmaxf(acc1[mi][2] + b2v[4 * mi + 2], 0.f);
        float a3 = fmaxf(acc1[mi][3] + b2v[4 * mi + 3], 0.f);
        aTd[w][8 * mi + 2 * g][c]     = pk2bf(a0, a1);
        aTd[w][8 * mi + 2 * g + 1][c] = pk2bf(a2, a3);
    }
    __syncthreads();  // waves touch only their own slice; barrier for LDS visibility

    // B-frags: a^T from LDS; elem pair (2i,2i+1) <-> j = 32kt+8g+2i -> row 16kt+4g+i
    short8 bfr[2];
#pragma unroll
    for (int kt = 0; kt < 2; ++kt) {
        short8 f;
#pragma unroll
        for (int i = 0; i < 4; ++i) {
            unsigned int d = aTd[w][16 * kt + 4 * g + i][c];
            f[2 * i]     = (short)(d & 0xffffu);
            f[2 * i + 1] = (short)(d >> 16);
        }
        bfr[kt] = f;
    }

    // GEMM-B: acc2[mt] = sum_kt W3^T x a^T  (D2[m][node])
    f32x4 acc2[2] = {{0.f, 0.f, 0.f, 0.f}, {0.f, 0.f, 0.f, 0.f}};
#pragma unroll
    for (int mt = 0; mt < 2; ++mt)
#pragma unroll
        for (int kt = 0; kt < 2; ++kt)
            acc2[mt] = __builtin_amdgcn_mfma_f32_16x16x32_bf16(w3f[mt][kt], bfr[kt], acc2[mt], 0, 0, 0);

    // store: m = 16mt + 4g + r, Hb3[node][m] bf16 (dword pairs, 8B-aligned)
    if (nv) {
        float di = dinv[node];
        unsigned short* o = Hb3 + (size_t)node * 32;
#pragma unroll
        for (int mt = 0; mt < 2; ++mt) {
            *(unsigned int*)(o + 16 * mt + 4 * g)     = pk2bf(acc2[mt][0] * di, acc2[mt][1] * di);
            *(unsigned int*)(o + 16 * mt + 4 * g + 2) = pk2bf(acc2[mt][2] * di, acc2[mt][3] * di);
        }
    }
}

// Head: cnt via binary search; pooled = sums/cnt + b3; a=relu(pooled@Wa+ba);
// out=tanh(a@Wo+bo)
__global__ void k_head(const float* __restrict__ sums, const int* __restrict__ batch, int N,
                       const float* __restrict__ b3,
                       const float* __restrict__ Wa, const float* __restrict__ ba,
                       const float* __restrict__ Wo, const float* __restrict__ bo,
                       float* __restrict__ out) {
    int g = blockIdx.x;
    int j = threadIdx.x;  // 64 threads
    int lo = 0, hi = N;
    while (lo < hi) { int m = (lo + hi) >> 1; if (batch[m] < g) lo = m + 1; else hi = m; }
    int start = lo;
    lo = start; hi = N;
    while (lo < hi) { int m = (lo + hi) >> 1; if (batch[m] < g + 1) lo = m + 1; else hi = m; }
    int cnt = lo - start;
    float inv = 1.0f / (float)(cnt > 0 ? cnt : 1);

    __shared__ float p[32];
    __shared__ float a[64];
    if (j < 32) p[j] = sums[g * 32 + j] * inv + b3[j];
    __syncthreads();
    float acc = ba[j];
#pragma unroll
    for (int k = 0; k < 32; ++k) acc += p[k] * Wa[k * 64 + j];
    a[j] = fmaxf(acc, 0.0f);
    __syncthreads();
    if (j < 32) {
        float acc2 = bo[j];
#pragma unroll
        for (int k = 0; k < 64; ++k) acc2 += a[k] * Wo[k * 32 + j];
        out[g * 32 + j] = tanhf(acc2);
    }
}

static inline int cdiv(long long a, int b) { return (int)((a + b - 1) / b); }
static inline size_t align256(size_t x) { return (x + 255) & ~(size_t)255; }

extern "C" void kernel_launch(void* const* d_in, const int* in_sizes, int n_in,
                              void* d_out, int out_size, void* d_ws, size_t ws_size,
                              hipStream_t stream) {
    const float* x     = (const float*)d_in[0];
    const int*   edge  = (const int*)d_in[1];
    const int*   batch = (const int*)d_in[2];
    const float* W1 = (const float*)d_in[3];  const float* b1 = (const float*)d_in[4];
    const float* W2 = (const float*)d_in[5];  const float* b2 = (const float*)d_in[6];
    const float* W3 = (const float*)d_in[7];  const float* b3 = (const float*)d_in[8];
    const float* Wa = (const float*)d_in[9];  const float* ba = (const float*)d_in[10];
    const float* Wo = (const float*)d_in[11]; const float* bo = (const float*)d_in[12];

    const int E = in_sizes[1] / 2;
    const int N = in_sizes[2];
    const int G = 64;
    const int NB = cdiv(N, 1 << BSH);     // 391
    const int NCH = cdiv(E, CH_E);        // 782

    const int* srcp = edge;
    const int* dstp = edge + E;

    // Workspace
    char* base = (char*)d_ws;
    size_t off = 0;
    float* dinv   = (float*)(base + off); off = align256(off + sizeof(float) * N);
    unsigned short* lp16 = (unsigned short*)(base + off); off = align256(off + sizeof(short) * E);
    int* cnt_mat  = (int*)(base + off); off = align256(off + sizeof(int) * (size_t)NB * NCH);
    int* offs_mat = (int*)(base + off); off = align256(off + sizeof(int) * (size_t)NB * NCH);
    int* btot     = (int*)(base + off); off = align256(off + sizeof(int) * (NB + 1));
    int* bbase    = (int*)(base + off); off = align256(off + sizeof(int) * (NB + 1));
    unsigned int* bedges = (unsigned int*)(base + off); off = align256(off + sizeof(int) * E);
    int* rowptr   = (int*)(base + off); off = align256(off + sizeof(int) * (N + 1));
    int* csr_src  = (int*)(base + off); off = align256(off + sizeof(int) * E);
    unsigned short* Hb1 = (unsigned short*)(base + off); off = align256(off + sizeof(short) * (size_t)N * 16);
    unsigned short* Hb2 = (unsigned short*)(base + off); off = align256(off + sizeof(short) * (size_t)N * 16);
    unsigned short* P2b = (unsigned short*)(base + off); off = align256(off + sizeof(short) * (size_t)N * 16);
    unsigned short* Hb3 = (unsigned short*)(base + off); off = align256(off + sizeof(short) * (size_t)N * 32);
    float* sums   = (float*)(base + off); off = align256(off + sizeof(float) * G * 32);

    // ---- Atomic-free binning -> bucket-sorted bedges ----
    k_countA<<<NCH, THREADS, 0, stream>>>(dstp, lp16, cnt_mat, E, NB, NCH);
    k_sumK1<<<NB, THREADS, 0, stream>>>(cnt_mat, btot, NCH);
    k_scanK2<<<1, MAXNB, 0, stream>>>(btot, bbase, rowptr, sums, NB, E, N, G * 32);
    k_scanK3<<<NB, THREADS, 0, stream>>>(cnt_mat, bbase, offs_mat, NCH);
    k_scatter2<<<NCH, THREADS, 0, stream>>>(srcp, dstp, lp16, cnt_mat, offs_mat, bedges, E, NB, NCH);

    // ---- CSR (rowptr, csr_src, dinv) from bucket-sorted edges ----
    k_bucket_csr<<<NB, TCSR, 0, stream>>>(bedges, bbase, rowptr, dinv, csr_src, N);

    // ---- Layer 1: Hb1 = bf16((x@W1)*dinv); pull16 -> Hb2 = bf16(relu(.+b1)*dinv) ----
    k_gemm1<<<cdiv(N, 64), THREADS, 0, stream>>>(x, W1, dinv, Hb1, N);
    k_pull<16, 1, 4><<<cdiv(N, 32), THREADS, 0, stream>>>(rowptr, csr_src, dinv, Hb1, b1, Hb2,
                                                          nullptr, nullptr, N, G);

    // ---- Layer 2 aggregate at input width: P2b = bf16(pull16(Hb2)) ----
    k_pull<16, 2, 4><<<cdiv(N, 32), THREADS, 0, stream>>>(rowptr, csr_src, dinv, Hb2, nullptr, P2b,
                                                          nullptr, nullptr, N, G);

    // ---- Fused node MLP (MFMA): Hb3 = bf16((relu(P2b@W2+b2)@W3)*dinv) ----
    k_mlp<<<cdiv(N, 64), THREADS, 0, stream>>>(P2b, W2, b2, W3, dinv, Hb3, N);

    // ---- Layer 3 aggregate fused with pooling: sums[g] += dinv*(agg+self) ----
    k_pull<32, 3, 2><<<cdiv(N, 32), THREADS, 0, stream>>>(rowptr, csr_src, dinv, Hb3, nullptr,
                                                          nullptr, batch, sums, N, G);

    // ---- Head (adds deferred b3) ----
    k_head<<<G, 64, 0, stream>>>(sums, batch, N, b3, Wa, ba, Wo, bo, (float*)d_out);
}